// Round 5
// baseline (448.151 us; speedup 1.0000x reference)
//
#include <hip/hip_runtime.h>
#include <stdint.h>

// Problem dims
#define T_TOT 32768   // B*S
#define H_DIM 1024
#define A_DIM 32
#define E_NUM 8
#define ED_DIM 256
#define RH_DIM 128
#define NBIG 2560     // 8*256 experts + 256 shared + 128 router + 128 value
#define K2 2304       // 8*256 + 256 (expert+shared h1 -> action)

typedef float f32x4 __attribute__((ext_vector_type(4)));
typedef short bf16x8 __attribute__((ext_vector_type(8)));
typedef unsigned short u16;
typedef u16 u16x8 __attribute__((ext_vector_type(8)));

typedef uint32_t __attribute__((address_space(1))) as1_u32;
typedef uint32_t __attribute__((address_space(3))) as3_u32;

__device__ __forceinline__ u16 f2bf(float f) {
    union { float f; uint32_t u; } v; v.f = f;
    return (u16)((v.u + 0x7FFFu + ((v.u >> 16) & 1u)) >> 16);  // RNE
}
__device__ __forceinline__ float bf2f(u16 h) {
    union { uint32_t u; float f; } v; v.u = ((uint32_t)h) << 16;
    return v.f;
}
__device__ __forceinline__ float gelu_erf(float x) {
    return 0.5f * x * (1.0f + erff(x * 0.70710678118654752f));
}
__device__ __forceinline__ void gload_lds16(const void* g, void* lds) {
    __builtin_amdgcn_global_load_lds((const as1_u32*)(uintptr_t)g,
                                     (as3_u32*)(uintptr_t)lds, 16, 0, 0);
}

// ---------------- setup kernels ----------------

__global__ void k_convert_x(const float* __restrict__ x, u16* __restrict__ xb, int n4) {
    int i = blockIdx.x * blockDim.x + threadIdx.x;
    if (i >= n4) return;
    float4 v = ((const float4*)x)[i];
    ushort4 o;
    o.x = f2bf(v.x); o.y = f2bf(v.y); o.z = f2bf(v.z); o.w = f2bf(v.w);
    ((ushort4*)xb)[i] = o;
}

// pack big W^T [NBIG][K=1024] bf16 + concatenated bias (fp32)
__global__ void k_pack_w(const float* __restrict__ ew1, const float* __restrict__ sw1,
                         const float* __restrict__ rw1, const float* __restrict__ vw1,
                         const float* __restrict__ eb1, const float* __restrict__ sb1,
                         const float* __restrict__ rb1, const float* __restrict__ vb1,
                         u16* __restrict__ wbf, float* __restrict__ biascat) {
    int t = blockIdx.x * blockDim.x + threadIdx.x;
    if (t >= NBIG * H_DIM) return;
    int n = t >> 10, k = t & 1023;
    float v;
    if (n < 2048)      v = ew1[(size_t)(((n >> 8) * H_DIM) + k) * ED_DIM + (n & 255)];
    else if (n < 2304) v = sw1[(size_t)k * ED_DIM + (n - 2048)];
    else if (n < 2432) v = rw1[(size_t)k * RH_DIM + (n - 2304)];
    else               v = vw1[(size_t)k * RH_DIM + (n - 2432)];
    wbf[t] = f2bf(v);
    if (k == 0) {
        float b;
        if (n < 2048)      b = eb1[(n >> 8) * ED_DIM + (n & 255)];
        else if (n < 2304) b = sb1[n - 2048];
        else if (n < 2432) b = rb1[n - 2304];
        else               b = vb1[n - 2432];
        biascat[n] = b;
    }
}

// pack second-layer weights transposed: W2T [32][2304] bf16 (expert | shared)
__global__ void k_pack_w2t(const float* __restrict__ ew2, const float* __restrict__ sw2,
                           u16* __restrict__ w2t) {
    int t = blockIdx.x * blockDim.x + threadIdx.x;
    if (t >= A_DIM * K2) return;
    int a = t / K2, d = t - a * K2;
    float v = (d < 2048) ? ew2[(size_t)d * A_DIM + a] : sw2[(size_t)(d - 2048) * A_DIM + a];
    w2t[t] = f2bf(v);
}

__global__ void k_cand(const float* __restrict__ base, float* __restrict__ outp) {
    int i = blockIdx.x * blockDim.x + threadIdx.x;
    if (i >= T_TOT * E_NUM * A_DIM) return;
    int a = i & 31, e = (i >> 5) & 7, t = i >> 8;
    outp[i] = base[(size_t)t * A_DIM + a] * (0.8f + 0.4f * (float)e / 7.0f);
}

// ---------------- GEMM1: X[Tx1024] @ Wbig -> H1[Tx2560] (act applied, bf16) ----------------
// 128x256 tile, BK=64, 512 threads / 8 waves (wave = 64x64 out).
// 3-deep LDS pipeline, counted vmcnt(6), ONE raw barrier per K-tile:
//   iter t: vmcnt(6) [tile t landed] ; s_barrier ; stage tile t+2 ; compute tile t.
// Loads get ~2 compute phases to cover HBM latency. Race-free: buf (t+2)%3 ==
// buf (t-1)%3 whose readers finished before this iter's barrier (ds_read
// results consumed into regs pre-barrier). Only in-loop VMEM = 6 gload_lds/tile,
// so vmcnt accounting is exact (no spills: launch_bounds caps VGPR at 256).
// T2 XOR swizzle: LDS slot s of row r holds global slot s^(r&7) (rule #21).

#define G1_BUFE 24576   // u16 elems per buffer: A 128x64 (8192) + B 256x64 (16384)

__launch_bounds__(512, 2)
__global__ void k_gemm1(const u16* __restrict__ xb, const u16* __restrict__ wbf,
                        const float* __restrict__ biascat, u16* __restrict__ h1) {
    __shared__ u16 smem[3 * G1_BUFE];   // 144 KB
    const int tid = threadIdx.x;
    const int wid = tid >> 6;           // 0..7
    const int lane = tid & 63;
    const int m0 = blockIdx.y * 128;
    const int n0 = blockIdx.x * 256;
    const int wr = wid >> 2;            // 0..1  (m half)
    const int wc = wid & 3;             // 0..3  (n quarter)
    const int rr = tid >> 3;            // 0..63 (staging row within 64-group)
    // pre-swizzled source column (elems): LDS slot (tid&7) gets global slot (tid&7)^(r&7)
    const int csrc = 8 * ((tid & 7) ^ (rr & 7));
    const int rxor = (lane & 7) * 8;    // read-side XOR: (row&7)*8 == (lane&7)*8
    const int lhi8 = (lane >> 4) * 8;

    f32x4 acc[4][4];
#pragma unroll
    for (int m = 0; m < 4; ++m)
#pragma unroll
        for (int n = 0; n < 4; ++n) acc[m][n] = (f32x4){0.f, 0.f, 0.f, 0.f};

    auto stage = [&](int b, int kt) {   // 6 gload_lds per thread
        const int k0 = kt * 64;
        u16* A = smem + b * G1_BUFE;
        u16* B = A + 8192;
#pragma unroll
        for (int j = 0; j < 2; ++j)
            gload_lds16(xb + (size_t)(m0 + j * 64 + rr) * H_DIM + k0 + csrc,
                        A + (j * 64 + wid * 8) * 64);
#pragma unroll
        for (int j = 0; j < 4; ++j)
            gload_lds16(wbf + (size_t)(n0 + j * 64 + rr) * H_DIM + k0 + csrc,
                        B + (j * 64 + wid * 8) * 64);
    };
    auto comp = [&](int b) {
        const u16* A = smem + b * G1_BUFE;
        const u16* B = A + 8192;
#pragma unroll
        for (int kk = 0; kk < 64; kk += 32) {
            bf16x8 av[4], bv[4];
#pragma unroll
            for (int m = 0; m < 4; ++m)
                av[m] = *(const bf16x8*)&A[(wr * 64 + m * 16 + (lane & 15)) * 64 + ((kk + lhi8) ^ rxor)];
#pragma unroll
            for (int n = 0; n < 4; ++n)
                bv[n] = *(const bf16x8*)&B[(wc * 64 + n * 16 + (lane & 15)) * 64 + ((kk + lhi8) ^ rxor)];
#pragma unroll
            for (int m = 0; m < 4; ++m)
#pragma unroll
                for (int n = 0; n < 4; ++n)
                    acc[m][n] = __builtin_amdgcn_mfma_f32_16x16x32_bf16(av[m], bv[n], acc[m][n], 0, 0, 0);
        }
    };

    stage(0, 0);
    stage(1, 1);
    for (int kt = 0; kt < 16; ++kt) {
        if (kt < 15) asm volatile("s_waitcnt vmcnt(6)" ::: "memory");
        else         asm volatile("s_waitcnt vmcnt(0)" ::: "memory");
        __builtin_amdgcn_s_barrier();
        if (kt < 14) stage((kt + 2) % 3, kt + 2);
        comp(kt % 3);
    }

    const int crow = (lane >> 4) * 4;
    const int ccol = lane & 15;
#pragma unroll
    for (int m = 0; m < 4; ++m) {
#pragma unroll
        for (int n = 0; n < 4; ++n) {
            const int col = n0 + wc * 64 + n * 16 + ccol;
            const float bias = biascat[col];
#pragma unroll
            for (int r = 0; r < 4; ++r) {
                const int row = m0 + wr * 64 + m * 16 + crow + r;
                float v = acc[m][n][r] + bias;
                v = (col < 2432) ? gelu_erf(v) : fmaxf(v, 0.f);  // gelu experts/shared/router, relu value
                h1[(size_t)row * NBIG + col] = f2bf(v);
            }
        }
    }
}

// ---------------- router softmax + value rtg ----------------

__global__ void k_router_value(const u16* __restrict__ h1,
                               const float* __restrict__ rw2, const float* __restrict__ rb2,
                               const float* __restrict__ vw2, const float* __restrict__ vb2,
                               float* __restrict__ probs_out, float* __restrict__ rtg_out) {
    __shared__ float rh[32][130];
    __shared__ float vh[32][130];
    __shared__ float w2[RH_DIM * E_NUM];
    __shared__ float vw[RH_DIM];
    const int tid = threadIdx.x;
    const int t0 = blockIdx.x * 32;
    for (int i = tid; i < RH_DIM * E_NUM; i += 256) w2[i] = rw2[i];
    if (tid < RH_DIM) vw[tid] = vw2[tid];
    {
        const int row = tid >> 3;
        const int c0 = (tid & 7) * 16;
        const u16* srcr = h1 + (size_t)(t0 + row) * NBIG + 2304 + c0;
        const u16* srcv = h1 + (size_t)(t0 + row) * NBIG + 2432 + c0;
        u16x8 a0 = *(const u16x8*)srcr;
        u16x8 a1 = *(const u16x8*)(srcr + 8);
        u16x8 b0 = *(const u16x8*)srcv;
        u16x8 b1 = *(const u16x8*)(srcv + 8);
#pragma unroll
        for (int j = 0; j < 8; ++j) {
            rh[row][c0 + j] = bf2f(a0[j]);
            rh[row][c0 + 8 + j] = bf2f(a1[j]);
            vh[row][c0 + j] = bf2f(b0[j]);
            vh[row][c0 + 8 + j] = bf2f(b1[j]);
        }
    }
    __syncthreads();
    const int tl = tid >> 3, a = tid & 7;
    float acc = rb2[a];
#pragma unroll 8
    for (int d = 0; d < RH_DIM; ++d) acc += rh[tl][d] * w2[d * E_NUM + a];
    float mx = acc;
    mx = fmaxf(mx, __shfl_xor(mx, 1));
    mx = fmaxf(mx, __shfl_xor(mx, 2));
    mx = fmaxf(mx, __shfl_xor(mx, 4));
    float ex = expf(acc - mx);
    float sm = ex;
    sm += __shfl_xor(sm, 1);
    sm += __shfl_xor(sm, 2);
    sm += __shfl_xor(sm, 4);
    probs_out[(size_t)(t0 + tl) * E_NUM + a] = ex / sm;
    float pv = 0.f;
#pragma unroll
    for (int j = 0; j < 16; ++j) pv += vh[tl][a * 16 + j] * vw[a * 16 + j];
    pv += __shfl_xor(pv, 1);
    pv += __shfl_xor(pv, 2);
    pv += __shfl_xor(pv, 4);
    if (a == 0) rtg_out[t0 + tl] = 1.f / (1.f + expf(-(pv + vb2[0])));
}

// ---------------- GEMM2: H1[Tx2304] @ W2T^T with per-expert prob fold -> weighted/moe ----------------

__launch_bounds__(256, 2)
__global__ void k_gemm2(const u16* __restrict__ h1, const u16* __restrict__ w2t,
                        const float* __restrict__ probs,
                        const float* __restrict__ eb2, const float* __restrict__ sb2,
                        float* __restrict__ moe_out, float* __restrict__ wgt_out) {
    __shared__ u16 As[2][128 * 64];
    __shared__ u16 Bs[2][32 * 64];
    __shared__ float plds[128 * E_NUM];
    const int tid = threadIdx.x;
    const int wid = tid >> 6;
    const int lane = tid & 63;
    const int m0 = blockIdx.x * 128;
    const int csrc = 8 * ((tid & 7) ^ ((tid >> 3) & 7));
    const int rxor = (lane & 7) * 8;
    const int lhi8 = (lane >> 4) * 8;
    const int crow = (lane >> 4) * 4;
    const int ccol = lane & 15;

    for (int i = tid; i < 128 * E_NUM; i += 256) plds[i] = probs[(size_t)m0 * E_NUM + i];

    f32x4 acc[2][2], accT[2][2], accS[2][2];
#pragma unroll
    for (int m = 0; m < 2; ++m)
#pragma unroll
        for (int n = 0; n < 2; ++n) {
            acc[m][n] = (f32x4){0.f, 0.f, 0.f, 0.f};
            accT[m][n] = (f32x4){0.f, 0.f, 0.f, 0.f};
            accS[m][n] = (f32x4){0.f, 0.f, 0.f, 0.f};
        }

    auto stage = [&](int buf, int kt) {
        const int k0 = kt * 64;
#pragma unroll
        for (int it = 0; it < 4; ++it) {
            const int r = it * 32 + (tid >> 3);
            gload_lds16(h1 + (size_t)(m0 + r) * NBIG + k0 + csrc, &As[buf][(it * 4 + wid) * 512]);
        }
        gload_lds16(w2t + (size_t)(tid >> 3) * K2 + k0 + csrc, &Bs[buf][wid * 512]);
    };

    stage(0, 0);
    __syncthreads();
    int cur = 0;
    for (int kt = 0; kt < 36; ++kt) {
        if (kt < 35) stage(cur ^ 1, kt + 1);
        const bool isExp = (kt < 32);
#pragma unroll
        for (int kk = 0; kk < 64; kk += 32) {
            bf16x8 av[2], bv[2];
#pragma unroll
            for (int m = 0; m < 2; ++m)
                av[m] = *(const bf16x8*)&As[cur][(wid * 32 + m * 16 + (lane & 15)) * 64 + ((kk + lhi8) ^ rxor)];
#pragma unroll
            for (int n = 0; n < 2; ++n)
                bv[n] = *(const bf16x8*)&Bs[cur][(n * 16 + (lane & 15)) * 64 + ((kk + lhi8) ^ rxor)];
            if (isExp) {
#pragma unroll
                for (int m = 0; m < 2; ++m)
#pragma unroll
                    for (int n = 0; n < 2; ++n)
                        acc[m][n] = __builtin_amdgcn_mfma_f32_16x16x32_bf16(av[m], bv[n], acc[m][n], 0, 0, 0);
            } else {
#pragma unroll
                for (int m = 0; m < 2; ++m)
#pragma unroll
                    for (int n = 0; n < 2; ++n)
                        accS[m][n] = __builtin_amdgcn_mfma_f32_16x16x32_bf16(av[m], bv[n], accS[m][n], 0, 0, 0);
            }
        }
        if (isExp && (kt & 3) == 3) {
            const int e = kt >> 2;
#pragma unroll
            for (int m = 0; m < 2; ++m)
#pragma unroll
                for (int r = 0; r < 4; ++r) {
                    const float p = plds[(wid * 32 + m * 16 + crow + r) * E_NUM + e];
#pragma unroll
                    for (int n = 0; n < 2; ++n) {
                        accT[m][n][r] += p * acc[m][n][r];
                        acc[m][n][r] = 0.f;
                    }
                }
        }
        __syncthreads();
        cur ^= 1;
    }

#pragma unroll
    for (int m = 0; m < 2; ++m) {
#pragma unroll
        for (int n = 0; n < 2; ++n) {
            const int aIdx = n * 16 + ccol;
#pragma unroll
            for (int r = 0; r < 4; ++r) {
                const int row = wid * 32 + m * 16 + crow + r;
                const int t = m0 + row;
                float wb = 0.f;
#pragma unroll
                for (int e = 0; e < E_NUM; ++e) wb += plds[row * E_NUM + e] * eb2[e * A_DIM + aIdx];
                const float w = accT[m][n][r] + wb;               // weighted_expert
                const float mo = w + accS[m][n][r] + sb2[aIdx];   // + shared_output
                wgt_out[(size_t)t * A_DIM + aIdx] = w;
                moe_out[(size_t)t * A_DIM + aIdx] = mo;
            }
        }
    }
}

// ---------------- residual MLP + final combine ----------------

__global__ void k_final(const float* __restrict__ moe, const float* __restrict__ wgt,
                        const float* __restrict__ mw1, const float* __restrict__ mb1,
                        const float* __restrict__ mw2, const float* __restrict__ mb2,
                        const float* __restrict__ mask, float* __restrict__ outp) {
    __shared__ float w1[A_DIM * RH_DIM];
    __shared__ float w2[RH_DIM * A_DIM];
    __shared__ float mo[32][33];
    __shared__ float rh[32][128];
    const int tid = threadIdx.x;
    const int t0 = blockIdx.x * 32;
    for (int i = tid; i < A_DIM * RH_DIM; i += 1024) { w1[i] = mw1[i]; w2[i] = mw2[i]; }
    const int tl = tid >> 5, a = tid & 31;
    mo[tl][a] = moe[(size_t)(t0 + tl) * A_DIM + a];
    __syncthreads();
#pragma unroll
    for (int jj = 0; jj < 4; ++jj) {
        const int j = a * 4 + jj;
        float s = mb1[j];
#pragma unroll
        for (int aa = 0; aa < 32; ++aa) s += mo[tl][aa] * w1[aa * RH_DIM + j];
        rh[tl][j] = gelu_erf(s);
    }
    __syncthreads();
    float s = mb2[a];
#pragma unroll
    for (int j = 0; j < RH_DIM; ++j) s += rh[tl][j] * w2[j * A_DIM + a];
    const float res = wgt[(size_t)(t0 + tl) * A_DIM + a] + s;
    outp[(size_t)(t0 + tl) * A_DIM + a] = res * mask[t0 + tl];
}

// ---------------- launch ----------------

extern "C" void kernel_launch(void* const* d_in, const int* in_sizes, int n_in,
                              void* d_out, int out_size, void* d_ws, size_t ws_size,
                              hipStream_t stream) {
    const float* state = (const float*)d_in[0];
    const float* base  = (const float*)d_in[1];
    const float* mask  = (const float*)d_in[2];
    const float* sw1 = (const float*)d_in[3];
    const float* sb1 = (const float*)d_in[4];
    const float* sw2 = (const float*)d_in[5];
    const float* sb2 = (const float*)d_in[6];
    const float* ew1 = (const float*)d_in[7];
    const float* eb1 = (const float*)d_in[8];
    const float* ew2 = (const float*)d_in[9];
    const float* eb2 = (const float*)d_in[10];
    const float* rw1 = (const float*)d_in[11];
    const float* rb1 = (const float*)d_in[12];
    const float* rw2 = (const float*)d_in[13];
    const float* rb2 = (const float*)d_in[14];
    const float* mw1 = (const float*)d_in[15];
    const float* mb1 = (const float*)d_in[16];
    const float* mw2 = (const float*)d_in[17];
    const float* mb2 = (const float*)d_in[18];
    const float* vw1 = (const float*)d_in[19];
    const float* vb1 = (const float*)d_in[20];
    const float* vw2 = (const float*)d_in[21];
    const float* vb2 = (const float*)d_in[22];

    float* out_final = (float*)d_out;                 // [32768][32]
    float* out_cand  = out_final + 1048576;           // [32768][8][32]
    float* out_probs = out_final + 9437184;           // [32768][8]
    float* out_rtg   = out_final + 9699328;           // [32768]

    // adaptive chunking: largest chunk whose ws footprint fits (deterministic in ws_size)
    auto al = [](size_t b) { return (b + 255) & ~(size_t)255; };
    auto need = [&](size_t T) {
        return al((size_t)NBIG * H_DIM * 2) + al((size_t)A_DIM * K2 * 2) + al((size_t)NBIG * 4)
             + al(T * H_DIM * 2) + al(T * NBIG * 2) + 2 * al(T * A_DIM * 4);
    };
    size_t Tc = 8192;
    if (need(32768) <= ws_size)      Tc = 32768;
    else if (need(16384) <= ws_size) Tc = 16384;
    const int nchunk = (int)(T_TOT / Tc);

    char* ws = (char*)d_ws;
    size_t off = 0;
    auto take = [&](size_t b) { char* p = ws + off; off += (b + 255) & ~(size_t)255; return p; };
    u16*   wbf   = (u16*)take((size_t)NBIG * H_DIM * 2);
    u16*   w2t   = (u16*)take((size_t)A_DIM * K2 * 2);
    float* bias  = (float*)take((size_t)NBIG * 4);
    u16*   xb    = (u16*)take(Tc * H_DIM * 2);
    u16*   h1    = (u16*)take(Tc * NBIG * 2);
    float* moe   = (float*)take(Tc * A_DIM * 4);
    float* wgt   = (float*)take(Tc * A_DIM * 4);
    (void)in_sizes; (void)n_in; (void)out_size;

    k_pack_w<<<(NBIG * H_DIM) / 256, 256, 0, stream>>>(ew1, sw1, rw1, vw1, eb1, sb1, rb1, vb1, wbf, bias);
    k_pack_w2t<<<(A_DIM * K2) / 256, 256, 0, stream>>>(ew2, sw2, w2t);
    k_cand<<<(T_TOT * E_NUM * A_DIM) / 256, 256, 0, stream>>>(base, out_cand);

    for (int c = 0; c < nchunk; ++c) {
        const size_t tb = (size_t)c * Tc;
        k_convert_x<<<(int)(Tc * H_DIM / 4 / 256), 256, 0, stream>>>(state + tb * H_DIM, xb, (int)(Tc * H_DIM / 4));
        k_gemm1<<<dim3(NBIG / 256, (int)(Tc / 128)), 512, 0, stream>>>(xb, wbf, bias, h1);
        k_router_value<<<(int)(Tc / 32), 256, 0, stream>>>(h1, rw2, rb2, vw2, vb2,
                                                           out_probs + tb * E_NUM, out_rtg + tb);
        k_gemm2<<<(int)(Tc / 128), 256, 0, stream>>>(h1, w2t, out_probs + tb * E_NUM, eb2, sb2, moe, wgt);
        k_final<<<(int)(Tc / 32), 1024, 0, stream>>>(moe, wgt, mw1, mb1, mw2, mb2, mask + tb, out_final + tb * A_DIM);
    }
}

// Round 6
// 398.114 us; speedup vs baseline: 1.1257x; 1.1257x over previous
//
#include <hip/hip_runtime.h>
#include <stdint.h>

// Problem dims
#define T_TOT 32768   // B*S
#define H_DIM 1024
#define A_DIM 32
#define E_NUM 8
#define ED_DIM 256
#define RH_DIM 128
#define NBIG 2560     // 8*256 experts + 256 shared + 128 router + 128 value
#define K2 2304       // 8*256 + 256 (expert+shared h1 -> action)

typedef float f32x4 __attribute__((ext_vector_type(4)));
typedef short bf16x8 __attribute__((ext_vector_type(8)));
typedef unsigned short u16;
typedef u16 u16x8 __attribute__((ext_vector_type(8)));

typedef uint32_t __attribute__((address_space(1))) as1_u32;
typedef uint32_t __attribute__((address_space(3))) as3_u32;

__device__ __forceinline__ u16 f2bf(float f) {
    union { float f; uint32_t u; } v; v.f = f;
    return (u16)((v.u + 0x7FFFu + ((v.u >> 16) & 1u)) >> 16);  // RNE
}
__device__ __forceinline__ float bf2f(u16 h) {
    union { uint32_t u; float f; } v; v.u = ((uint32_t)h) << 16;
    return v.f;
}
__device__ __forceinline__ float gelu_erf(float x) {
    return 0.5f * x * (1.0f + erff(x * 0.70710678118654752f));
}
__device__ __forceinline__ void gload_lds16(const void* g, void* lds) {
    __builtin_amdgcn_global_load_lds((const as1_u32*)(uintptr_t)g,
                                     (as3_u32*)(uintptr_t)lds, 16, 0, 0);
}

// ---------------- setup kernels ----------------

__global__ void k_convert_x(const float* __restrict__ x, u16* __restrict__ xb, int n4) {
    int i = blockIdx.x * blockDim.x + threadIdx.x;
    if (i >= n4) return;
    float4 v = ((const float4*)x)[i];
    ushort4 o;
    o.x = f2bf(v.x); o.y = f2bf(v.y); o.z = f2bf(v.z); o.w = f2bf(v.w);
    ((ushort4*)xb)[i] = o;
}

// pack big W^T [NBIG][K=1024] bf16 + concatenated bias (fp32)
__global__ void k_pack_w(const float* __restrict__ ew1, const float* __restrict__ sw1,
                         const float* __restrict__ rw1, const float* __restrict__ vw1,
                         const float* __restrict__ eb1, const float* __restrict__ sb1,
                         const float* __restrict__ rb1, const float* __restrict__ vb1,
                         u16* __restrict__ wbf, float* __restrict__ biascat) {
    int t = blockIdx.x * blockDim.x + threadIdx.x;
    if (t >= NBIG * H_DIM) return;
    int n = t >> 10, k = t & 1023;
    float v;
    if (n < 2048)      v = ew1[(size_t)(((n >> 8) * H_DIM) + k) * ED_DIM + (n & 255)];
    else if (n < 2304) v = sw1[(size_t)k * ED_DIM + (n - 2048)];
    else if (n < 2432) v = rw1[(size_t)k * RH_DIM + (n - 2304)];
    else               v = vw1[(size_t)k * RH_DIM + (n - 2432)];
    wbf[t] = f2bf(v);
    if (k == 0) {
        float b;
        if (n < 2048)      b = eb1[(n >> 8) * ED_DIM + (n & 255)];
        else if (n < 2304) b = sb1[n - 2048];
        else if (n < 2432) b = rb1[n - 2304];
        else               b = vb1[n - 2432];
        biascat[n] = b;
    }
}

// pack second-layer weights transposed: W2T [32][2304] bf16 (expert | shared)
__global__ void k_pack_w2t(const float* __restrict__ ew2, const float* __restrict__ sw2,
                           u16* __restrict__ w2t) {
    int t = blockIdx.x * blockDim.x + threadIdx.x;
    if (t >= A_DIM * K2) return;
    int a = t / K2, d = t - a * K2;
    float v = (d < 2048) ? ew2[(size_t)d * A_DIM + a] : sw2[(size_t)(d - 2048) * A_DIM + a];
    w2t[t] = f2bf(v);
}

__global__ void k_cand(const float* __restrict__ base, float* __restrict__ outp) {
    int i = blockIdx.x * blockDim.x + threadIdx.x;
    if (i >= T_TOT * E_NUM * A_DIM) return;
    int a = i & 31, e = (i >> 5) & 7, t = i >> 8;
    outp[i] = base[(size_t)t * A_DIM + a] * (0.8f + 0.4f * (float)e / 7.0f);
}

// ---------------- GEMM1: X[Tx1024] @ Wbig -> H1[Tx2560] (act applied, bf16) ----------------
// 128x128 tile, BK=32, 256 threads / 4 waves, double-buffered 32 KB LDS
// -> 4 blocks/CU (launch_bounds(256,4)): cross-block overlap hides barrier
// drains (round-5 lesson: 1 block/CU lockstep was the regression).
// Known-good dbuf schedule: stage(t+1); comp(t); __syncthreads.
// T2 swizzle for 64B rows (4 x 16B slots): LDS slot s of row r holds global
// slot s^((r>>1)&3); under the 8-lane/cycle LDS service pattern each 8-lane
// group hits 8 distinct bank-quads (conflict-free; 128B-row analog measured 0).
// XCD-aware bijective blockIdx swizzle (T1): nwg divisible by 8.

__launch_bounds__(256, 4)
__global__ void k_gemm1(const u16* __restrict__ xb, const u16* __restrict__ wbf,
                        const float* __restrict__ biascat, u16* __restrict__ h1) {
    __shared__ u16 As[2][128 * 32];
    __shared__ u16 Bs[2][128 * 32];
    const int tid = threadIdx.x;
    const int wid = tid >> 6;
    const int lane = tid & 63;
    // XCD swizzle: contiguous chunk of grid per XCD
    const int lin = blockIdx.x;
    const int swz = (lin & 7) * ((int)gridDim.x >> 3) + (lin >> 3);
    const int bx = swz % 20;            // n-tile (NBIG/128 = 20)
    const int by = swz / 20;            // m-tile
    const int m0 = by * 128;
    const int n0 = bx * 128;
    const int wr = wid >> 1, wc = wid & 1;
    // staging: row rr = tid>>2 (64 rows/round), slot tid&3
    const int rr = tid >> 2;
    const int cs = 8 * ((tid & 3) ^ ((tid >> 3) & 3));   // pre-swizzled global slot
    // read swizzle: sw(row) = (row>>1)&3, row ≡ lane&15 (mod 16) -> (lane>>1)&3
    const int rcol = (((lane >> 4) ^ ((lane >> 1) & 3)) * 8);

    f32x4 acc[4][4];
#pragma unroll
    for (int m = 0; m < 4; ++m)
#pragma unroll
        for (int n = 0; n < 4; ++n) acc[m][n] = (f32x4){0.f, 0.f, 0.f, 0.f};

    auto stage = [&](int b, int kt) {   // 4 gload_lds per thread
        const int k0 = kt * 32;
#pragma unroll
        for (int j = 0; j < 2; ++j)
            gload_lds16(xb + (size_t)(m0 + j * 64 + rr) * H_DIM + k0 + cs,
                        &As[b][j * 2048 + wid * 512]);
#pragma unroll
        for (int j = 0; j < 2; ++j)
            gload_lds16(wbf + (size_t)(n0 + j * 64 + rr) * H_DIM + k0 + cs,
                        &Bs[b][j * 2048 + wid * 512]);
    };
    auto comp = [&](int b) {
        bf16x8 av[4], bv[4];
#pragma unroll
        for (int m = 0; m < 4; ++m)
            av[m] = *(const bf16x8*)&As[b][(wr * 64 + m * 16 + (lane & 15)) * 32 + rcol];
#pragma unroll
        for (int n = 0; n < 4; ++n)
            bv[n] = *(const bf16x8*)&Bs[b][(wc * 64 + n * 16 + (lane & 15)) * 32 + rcol];
#pragma unroll
        for (int m = 0; m < 4; ++m)
#pragma unroll
            for (int n = 0; n < 4; ++n)
                acc[m][n] = __builtin_amdgcn_mfma_f32_16x16x32_bf16(av[m], bv[n], acc[m][n], 0, 0, 0);
    };

    stage(0, 0);
    __syncthreads();
    int cur = 0;
    for (int kt = 0; kt < 32; ++kt) {
        if (kt < 31) stage(cur ^ 1, kt + 1);   // overlap next-tile loads with compute
        comp(cur);
        __syncthreads();
        cur ^= 1;
    }

    const int crow = (lane >> 4) * 4;
    const int ccol = lane & 15;
#pragma unroll
    for (int m = 0; m < 4; ++m) {
#pragma unroll
        for (int n = 0; n < 4; ++n) {
            const int col = n0 + wc * 64 + n * 16 + ccol;
            const float bias = biascat[col];
#pragma unroll
            for (int r = 0; r < 4; ++r) {
                const int row = m0 + wr * 64 + m * 16 + crow + r;
                float v = acc[m][n][r] + bias;
                v = (col < 2432) ? gelu_erf(v) : fmaxf(v, 0.f);  // gelu experts/shared/router, relu value
                h1[(size_t)row * NBIG + col] = f2bf(v);
            }
        }
    }
}

// ---------------- router softmax + value rtg ----------------

__global__ void k_router_value(const u16* __restrict__ h1,
                               const float* __restrict__ rw2, const float* __restrict__ rb2,
                               const float* __restrict__ vw2, const float* __restrict__ vb2,
                               float* __restrict__ probs_out, float* __restrict__ rtg_out) {
    __shared__ float rh[32][130];
    __shared__ float vh[32][130];
    __shared__ float w2[RH_DIM * E_NUM];
    __shared__ float vw[RH_DIM];
    const int tid = threadIdx.x;
    const int t0 = blockIdx.x * 32;
    for (int i = tid; i < RH_DIM * E_NUM; i += 256) w2[i] = rw2[i];
    if (tid < RH_DIM) vw[tid] = vw2[tid];
    {
        const int row = tid >> 3;
        const int c0 = (tid & 7) * 16;
        const u16* srcr = h1 + (size_t)(t0 + row) * NBIG + 2304 + c0;
        const u16* srcv = h1 + (size_t)(t0 + row) * NBIG + 2432 + c0;
        u16x8 a0 = *(const u16x8*)srcr;
        u16x8 a1 = *(const u16x8*)(srcr + 8);
        u16x8 b0 = *(const u16x8*)srcv;
        u16x8 b1 = *(const u16x8*)(srcv + 8);
#pragma unroll
        for (int j = 0; j < 8; ++j) {
            rh[row][c0 + j] = bf2f(a0[j]);
            rh[row][c0 + 8 + j] = bf2f(a1[j]);
            vh[row][c0 + j] = bf2f(b0[j]);
            vh[row][c0 + 8 + j] = bf2f(b1[j]);
        }
    }
    __syncthreads();
    const int tl = tid >> 3, a = tid & 7;
    float acc = rb2[a];
#pragma unroll 8
    for (int d = 0; d < RH_DIM; ++d) acc += rh[tl][d] * w2[d * E_NUM + a];
    float mx = acc;
    mx = fmaxf(mx, __shfl_xor(mx, 1));
    mx = fmaxf(mx, __shfl_xor(mx, 2));
    mx = fmaxf(mx, __shfl_xor(mx, 4));
    float ex = expf(acc - mx);
    float sm = ex;
    sm += __shfl_xor(sm, 1);
    sm += __shfl_xor(sm, 2);
    sm += __shfl_xor(sm, 4);
    probs_out[(size_t)(t0 + tl) * E_NUM + a] = ex / sm;
    float pv = 0.f;
#pragma unroll
    for (int j = 0; j < 16; ++j) pv += vh[tl][a * 16 + j] * vw[a * 16 + j];
    pv += __shfl_xor(pv, 1);
    pv += __shfl_xor(pv, 2);
    pv += __shfl_xor(pv, 4);
    if (a == 0) rtg_out[t0 + tl] = 1.f / (1.f + expf(-(pv + vb2[0])));
}

// ---------------- GEMM2: H1[Tx2304] @ W2T^T with per-expert prob fold -> weighted/moe ----------------
// BM=64 -> 512 blocks (2/CU) fixes the 1-block/CU grid starvation.
// Expert e owns K-tiles 4e..4e+3; unscaled partial accE folded into accT with
// prob p (f32) after each expert. BK=64, 8-slot XOR swizzle (rule #21).

__launch_bounds__(256, 4)
__global__ void k_gemm2(const u16* __restrict__ h1, const u16* __restrict__ w2t,
                        const float* __restrict__ probs,
                        const float* __restrict__ eb2, const float* __restrict__ sb2,
                        float* __restrict__ moe_out, float* __restrict__ wgt_out) {
    __shared__ u16 As[2][64 * 64];
    __shared__ u16 Bs[2][32 * 64];
    __shared__ float plds[64 * E_NUM];
    const int tid = threadIdx.x;
    const int wid = tid >> 6;
    const int lane = tid & 63;
    const int m0 = blockIdx.x * 64;
    const int csrc = 8 * ((tid & 7) ^ ((tid >> 3) & 7));
    const int rxor = (lane & 7) * 8;
    const int lhi8 = (lane >> 4) * 8;
    const int crow = (lane >> 4) * 4;
    const int ccol = lane & 15;

    for (int i = tid; i < 64 * E_NUM; i += 256) plds[i] = probs[(size_t)m0 * E_NUM + i];

    f32x4 accE[2], accT[2], accS[2];
#pragma unroll
    for (int n = 0; n < 2; ++n) {
        accE[n] = (f32x4){0.f, 0.f, 0.f, 0.f};
        accT[n] = (f32x4){0.f, 0.f, 0.f, 0.f};
        accS[n] = (f32x4){0.f, 0.f, 0.f, 0.f};
    }

    auto stage = [&](int buf, int kt) {   // 3 gload_lds per thread
        const int k0 = kt * 64;
#pragma unroll
        for (int j = 0; j < 2; ++j)       // A: 64 rows, 2 rounds of 32
            gload_lds16(h1 + (size_t)(m0 + j * 32 + (tid >> 3)) * NBIG + k0 + csrc,
                        &As[buf][j * 2048 + wid * 512]);
        gload_lds16(w2t + (size_t)(tid >> 3) * K2 + k0 + csrc, &Bs[buf][wid * 512]);
    };

    stage(0, 0);
    __syncthreads();
    int cur = 0;
    for (int kt = 0; kt < 36; ++kt) {
        if (kt < 35) stage(cur ^ 1, kt + 1);
        const bool isExp = (kt < 32);
#pragma unroll
        for (int kk = 0; kk < 64; kk += 32) {
            bf16x8 av = *(const bf16x8*)&As[cur][(wid * 16 + (lane & 15)) * 64 + ((kk + lhi8) ^ rxor)];
            bf16x8 bv0 = *(const bf16x8*)&Bs[cur][((lane & 15)) * 64 + ((kk + lhi8) ^ rxor)];
            bf16x8 bv1 = *(const bf16x8*)&Bs[cur][(16 + (lane & 15)) * 64 + ((kk + lhi8) ^ rxor)];
            if (isExp) {
                accE[0] = __builtin_amdgcn_mfma_f32_16x16x32_bf16(av, bv0, accE[0], 0, 0, 0);
                accE[1] = __builtin_amdgcn_mfma_f32_16x16x32_bf16(av, bv1, accE[1], 0, 0, 0);
            } else {
                accS[0] = __builtin_amdgcn_mfma_f32_16x16x32_bf16(av, bv0, accS[0], 0, 0, 0);
                accS[1] = __builtin_amdgcn_mfma_f32_16x16x32_bf16(av, bv1, accS[1], 0, 0, 0);
            }
        }
        if (isExp && (kt & 3) == 3) {
            const int e = kt >> 2;
#pragma unroll
            for (int r = 0; r < 4; ++r) {
                const float p = plds[(wid * 16 + crow + r) * E_NUM + e];
#pragma unroll
                for (int n = 0; n < 2; ++n) {
                    accT[n][r] += p * accE[n][r];
                    accE[n][r] = 0.f;
                }
            }
        }
        __syncthreads();
        cur ^= 1;
    }

#pragma unroll
    for (int n = 0; n < 2; ++n) {
        const int aIdx = n * 16 + ccol;
#pragma unroll
        for (int r = 0; r < 4; ++r) {
            const int row = wid * 16 + crow + r;
            const int t = m0 + row;
            float wb = 0.f;
#pragma unroll
            for (int e = 0; e < E_NUM; ++e) wb += plds[row * E_NUM + e] * eb2[e * A_DIM + aIdx];
            const float w = accT[n][r] + wb;              // weighted_expert
            const float mo = w + accS[n][r] + sb2[aIdx];  // + shared_output
            wgt_out[(size_t)t * A_DIM + aIdx] = w;
            moe_out[(size_t)t * A_DIM + aIdx] = mo;
        }
    }
}

// ---------------- residual MLP + final combine ----------------

__global__ void k_final(const float* __restrict__ moe, const float* __restrict__ wgt,
                        const float* __restrict__ mw1, const float* __restrict__ mb1,
                        const float* __restrict__ mw2, const float* __restrict__ mb2,
                        const float* __restrict__ mask, float* __restrict__ outp) {
    __shared__ float w1[A_DIM * RH_DIM];
    __shared__ float w2[RH_DIM * A_DIM];
    __shared__ float mo[32][33];
    __shared__ float rh[32][128];
    const int tid = threadIdx.x;
    const int t0 = blockIdx.x * 32;
    for (int i = tid; i < A_DIM * RH_DIM; i += 1024) { w1[i] = mw1[i]; w2[i] = mw2[i]; }
    const int tl = tid >> 5, a = tid & 31;
    mo[tl][a] = moe[(size_t)(t0 + tl) * A_DIM + a];
    __syncthreads();
#pragma unroll
    for (int jj = 0; jj < 4; ++jj) {
        const int j = a * 4 + jj;
        float s = mb1[j];
#pragma unroll
        for (int aa = 0; aa < 32; ++aa) s += mo[tl][aa] * w1[aa * RH_DIM + j];
        rh[tl][j] = gelu_erf(s);
    }
    __syncthreads();
    float s = mb2[a];
#pragma unroll
    for (int j = 0; j < RH_DIM; ++j) s += rh[tl][j] * w2[j * A_DIM + a];
    const float res = wgt[(size_t)(t0 + tl) * A_DIM + a] + s;
    outp[(size_t)(t0 + tl) * A_DIM + a] = res * mask[t0 + tl];
}

// ---------------- launch ----------------

extern "C" void kernel_launch(void* const* d_in, const int* in_sizes, int n_in,
                              void* d_out, int out_size, void* d_ws, size_t ws_size,
                              hipStream_t stream) {
    const float* state = (const float*)d_in[0];
    const float* base  = (const float*)d_in[1];
    const float* mask  = (const float*)d_in[2];
    const float* sw1 = (const float*)d_in[3];
    const float* sb1 = (const float*)d_in[4];
    const float* sw2 = (const float*)d_in[5];
    const float* sb2 = (const float*)d_in[6];
    const float* ew1 = (const float*)d_in[7];
    const float* eb1 = (const float*)d_in[8];
    const float* ew2 = (const float*)d_in[9];
    const float* eb2 = (const float*)d_in[10];
    const float* rw1 = (const float*)d_in[11];
    const float* rb1 = (const float*)d_in[12];
    const float* rw2 = (const float*)d_in[13];
    const float* rb2 = (const float*)d_in[14];
    const float* mw1 = (const float*)d_in[15];
    const float* mb1 = (const float*)d_in[16];
    const float* mw2 = (const float*)d_in[17];
    const float* mb2 = (const float*)d_in[18];
    const float* vw1 = (const float*)d_in[19];
    const float* vb1 = (const float*)d_in[20];
    const float* vw2 = (const float*)d_in[21];
    const float* vb2 = (const float*)d_in[22];

    float* out_final = (float*)d_out;                 // [32768][32]
    float* out_cand  = out_final + 1048576;           // [32768][8][32]
    float* out_probs = out_final + 9437184;           // [32768][8]
    float* out_rtg   = out_final + 9699328;           // [32768]

    // adaptive chunking: largest chunk whose ws footprint fits (deterministic in ws_size)
    auto al = [](size_t b) { return (b + 255) & ~(size_t)255; };
    auto need = [&](size_t T) {
        return al((size_t)NBIG * H_DIM * 2) + al((size_t)A_DIM * K2 * 2) + al((size_t)NBIG * 4)
             + al(T * H_DIM * 2) + al(T * NBIG * 2) + 2 * al(T * A_DIM * 4);
    };
    size_t Tc = 8192;
    if (need(32768) <= ws_size)      Tc = 32768;
    else if (need(16384) <= ws_size) Tc = 16384;
    const int nchunk = (int)(T_TOT / Tc);

    char* ws = (char*)d_ws;
    size_t off = 0;
    auto take = [&](size_t b) { char* p = ws + off; off += (b + 255) & ~(size_t)255; return p; };
    u16*   wbf   = (u16*)take((size_t)NBIG * H_DIM * 2);
    u16*   w2t   = (u16*)take((size_t)A_DIM * K2 * 2);
    float* bias  = (float*)take((size_t)NBIG * 4);
    u16*   xb    = (u16*)take(Tc * H_DIM * 2);
    u16*   h1    = (u16*)take(Tc * NBIG * 2);
    float* moe   = (float*)take(Tc * A_DIM * 4);
    float* wgt   = (float*)take(Tc * A_DIM * 4);
    (void)in_sizes; (void)n_in; (void)out_size;

    k_pack_w<<<(NBIG * H_DIM) / 256, 256, 0, stream>>>(ew1, sw1, rw1, vw1, eb1, sb1, rb1, vb1, wbf, bias);
    k_pack_w2t<<<(A_DIM * K2) / 256, 256, 0, stream>>>(ew2, sw2, w2t);
    k_cand<<<(T_TOT * E_NUM * A_DIM) / 256, 256, 0, stream>>>(base, out_cand);

    for (int c = 0; c < nchunk; ++c) {
        const size_t tb = (size_t)c * Tc;
        k_convert_x<<<(int)(Tc * H_DIM / 4 / 256), 256, 0, stream>>>(state + tb * H_DIM, xb, (int)(Tc * H_DIM / 4));
        k_gemm1<<<(NBIG / 128) * (int)(Tc / 128), 256, 0, stream>>>(xb, wbf, bias, h1);
        k_router_value<<<(int)(Tc / 32), 256, 0, stream>>>(h1, rw2, rb2, vw2, vb2,
                                                           out_probs + tb * E_NUM, out_rtg + tb);
        k_gemm2<<<(int)(Tc / 64), 256, 0, stream>>>(h1, w2t, out_probs + tb * E_NUM, eb2, sb2, moe, wgt);
        k_final<<<(int)(Tc / 32), 1024, 0, stream>>>(moe, wgt, mw1, mb1, mw2, mb2, mask + tb, out_final + tb * A_DIM);
    }
}

// Round 7
// 395.380 us; speedup vs baseline: 1.1335x; 1.0069x over previous
//
#include <hip/hip_runtime.h>
#include <stdint.h>

// Problem dims
#define T_TOT 32768   // B*S
#define H_DIM 1024
#define A_DIM 32
#define E_NUM 8
#define ED_DIM 256
#define RH_DIM 128
#define NBIG 2560     // 8*256 experts + 256 shared + 128 router + 128 value
#define K2 2304       // 8*256 + 256 (expert+shared h1 -> action)

typedef float f32x4 __attribute__((ext_vector_type(4)));
typedef short bf16x8 __attribute__((ext_vector_type(8)));
typedef unsigned short u16;
typedef u16 u16x8 __attribute__((ext_vector_type(8)));

typedef uint32_t __attribute__((address_space(1))) as1_u32;
typedef uint32_t __attribute__((address_space(3))) as3_u32;

__device__ __forceinline__ u16 f2bf(float f) {
    union { float f; uint32_t u; } v; v.f = f;
    return (u16)((v.u + 0x7FFFu + ((v.u >> 16) & 1u)) >> 16);  // RNE
}
__device__ __forceinline__ float bf2f(u16 h) {
    union { uint32_t u; float f; } v; v.u = ((uint32_t)h) << 16;
    return v.f;
}
__device__ __forceinline__ float gelu_erf(float x) {
    return 0.5f * x * (1.0f + erff(x * 0.70710678118654752f));
}
__device__ __forceinline__ void gload_lds16(const void* g, void* lds) {
    __builtin_amdgcn_global_load_lds((const as1_u32*)(uintptr_t)g,
                                     (as3_u32*)(uintptr_t)lds, 16, 0, 0);
}

// ---------------- setup kernels ----------------

__global__ void k_convert_x(const float* __restrict__ x, u16* __restrict__ xb, int n4) {
    int i = blockIdx.x * blockDim.x + threadIdx.x;
    if (i >= n4) return;
    float4 v = ((const float4*)x)[i];
    ushort4 o;
    o.x = f2bf(v.x); o.y = f2bf(v.y); o.z = f2bf(v.z); o.w = f2bf(v.w);
    ((ushort4*)xb)[i] = o;
}

// pack big W^T [NBIG][K=1024] bf16 + concatenated bias (fp32)
__global__ void k_pack_w(const float* __restrict__ ew1, const float* __restrict__ sw1,
                         const float* __restrict__ rw1, const float* __restrict__ vw1,
                         const float* __restrict__ eb1, const float* __restrict__ sb1,
                         const float* __restrict__ rb1, const float* __restrict__ vb1,
                         u16* __restrict__ wbf, float* __restrict__ biascat) {
    int t = blockIdx.x * blockDim.x + threadIdx.x;
    if (t >= NBIG * H_DIM) return;
    int n = t >> 10, k = t & 1023;
    float v;
    if (n < 2048)      v = ew1[(size_t)(((n >> 8) * H_DIM) + k) * ED_DIM + (n & 255)];
    else if (n < 2304) v = sw1[(size_t)k * ED_DIM + (n - 2048)];
    else if (n < 2432) v = rw1[(size_t)k * RH_DIM + (n - 2304)];
    else               v = vw1[(size_t)k * RH_DIM + (n - 2432)];
    wbf[t] = f2bf(v);
    if (k == 0) {
        float b;
        if (n < 2048)      b = eb1[(n >> 8) * ED_DIM + (n & 255)];
        else if (n < 2304) b = sb1[n - 2048];
        else if (n < 2432) b = rb1[n - 2304];
        else               b = vb1[n - 2432];
        biascat[n] = b;
    }
}

// pack second-layer weights transposed: W2T [32][2304] bf16 (expert | shared)
__global__ void k_pack_w2t(const float* __restrict__ ew2, const float* __restrict__ sw2,
                           u16* __restrict__ w2t) {
    int t = blockIdx.x * blockDim.x + threadIdx.x;
    if (t >= A_DIM * K2) return;
    int a = t / K2, d = t - a * K2;
    float v = (d < 2048) ? ew2[(size_t)d * A_DIM + a] : sw2[(size_t)(d - 2048) * A_DIM + a];
    w2t[t] = f2bf(v);
}

__global__ void k_cand(const float* __restrict__ base, float* __restrict__ outp) {
    int i = blockIdx.x * blockDim.x + threadIdx.x;
    if (i >= T_TOT * E_NUM * A_DIM) return;
    int a = i & 31, e = (i >> 5) & 7, t = i >> 8;
    outp[i] = base[(size_t)t * A_DIM + a] * (0.8f + 0.4f * (float)e / 7.0f);
}

// ---------------- GEMM1: X[Tx1024] @ Wbig -> H1[Tx2560] ----------------
// m201-style schedule (T2+T3+T4+T5), re-derived as a half-tile ring:
//   BM=BN=256, BK=64, 512 thr / 8 waves (2M x 4N), per-wave out 128x64
//   (m-frags interleaved: rows wr*16 + j*32, j=0..7 -> A-halves die in phase order).
//   LDS = ring of 8 slots x 16KB (128 rows x 64 k, one matrix half) = 128 KB.
//   Slot map: tile kt: A-half h -> (kt&1)*4+h, B-half h -> (kt&1)*4+2+h.
//   K-tile = 4 phases; phase q computes m-frags {2q,2q+1} x 4 n x kk{0,32} = 16 MFMA.
//   B-frags for the whole tile read once at P0 into regs (32 VGPR).
//   Phase = { ds_read A (4xb128; P0 also 8xb128 B); issue 1 half stage;
//             [vmcnt(8)@P1 | vmcnt(6)@P3]; s_barrier; lgkmcnt(0); sched_barrier;
//             setprio(1); 16 MFMA; setprio(0) }.
//   Stage plan per tile t: P0->Ah0(t+1), P1->Ah1(t+1), P2->Bh0(t+2), P3->Bh1(t+2).
//   vmcnt accounting (verified): @P1 retires Ah1(t) (consumed P2/P3);
//   @P3 retires {Bh0,Bh1,Ah0}(t+1) (consumed P0/P1 of t+1). 3 halves always in
//   flight; never vmcnt(0) in-loop. Every overwrite lands >=4 phases after its
//   slot's last read, with an all-waves barrier in between (race-free).
//   T2 swizzle: LDS slot s of row r holds global slot s^(r&7); read XORs it back.

#define SLOT 8192   // u16 per 16KB slot (128 rows x 64)

__launch_bounds__(512, 2)
__global__ void k_gemm1(const u16* __restrict__ xb, const u16* __restrict__ wbf,
                        const float* __restrict__ biascat, u16* __restrict__ h1) {
    __shared__ u16 smem[8 * SLOT];   // 128 KB
    const int tid = threadIdx.x;
    const int wid = tid >> 6;
    const int lane = tid & 63;
    // XCD-aware bijective swizzle (gridDim.x divisible by 8)
    const int lin = blockIdx.x;
    const int swz = (lin & 7) * ((int)gridDim.x >> 3) + (lin >> 3);
    const int bx = swz % 10;            // n-tile (NBIG/256 = 10)
    const int by = swz / 10;            // m-tile
    const int m0 = by * 256, n0 = bx * 256;
    const int wr = wid >> 2;            // 0..1 (m group)
    const int wc = wid & 3;             // 0..3 (n quarter)
    // staging addresses
    const int srow = tid >> 3;                              // 0..63
    const int cs = 8 * ((tid & 7) ^ (srow & 7));            // pre-swizzled col slot
    // read addresses
    const int l15 = lane & 15;
    const int rsw = (lane & 7) * 8;                         // read-side XOR
    const int lh8 = (lane >> 4) * 8;
    const int c0 = lh8 ^ rsw;                               // kk=0 col
    const int c1 = (32 + lh8) ^ rsw;                        // kk=1 col
    const int aRd = (wr * 16 + l15) * 64;                   // + (j&3)*2048 per frag
    const int bRd = ((wc & 1) * 64 + l15) * 64;             // + ni*1024 per frag
    const int bSlotHi = wc >> 1;                            // which B half this wave reads

    f32x4 acc[8][4];
#pragma unroll
    for (int j = 0; j < 8; ++j)
#pragma unroll
        for (int n = 0; n < 4; ++n) acc[j][n] = (f32x4){0.f, 0.f, 0.f, 0.f};

    auto stageA = [&](int h, int kt, int s) {   // 2 gload_lds
        const u16* src = xb + (size_t)(m0 + h * 128 + srow) * H_DIM + kt * 64 + cs;
        u16* dst = smem + s * SLOT + wid * 512;
        gload_lds16(src, dst);
        gload_lds16(src + (size_t)64 * H_DIM, dst + 4096);
    };
    auto stageB = [&](int h, int kt, int s) {
        const u16* src = wbf + (size_t)(n0 + h * 128 + srow) * H_DIM + kt * 64 + cs;
        u16* dst = smem + s * SLOT + wid * 512;
        gload_lds16(src, dst);
        gload_lds16(src + (size_t)64 * H_DIM, dst + 4096);
    };

    bf16x8 bfr[4][2];

#define G1_READA(q, P, A0, A1)                                                    \
    {                                                                             \
        const u16* ab0 = smem + ((P) * 4 + ((q) >> 1)) * SLOT + aRd + (((2*(q)) & 3) * 2048);     \
        const u16* ab1 = smem + ((P) * 4 + ((q) >> 1)) * SLOT + aRd + (((2*(q)+1) & 3) * 2048);   \
        A0[0] = *(const bf16x8*)&ab0[c0]; A0[1] = *(const bf16x8*)&ab0[c1];       \
        A1[0] = *(const bf16x8*)&ab1[c0]; A1[1] = *(const bf16x8*)&ab1[c1];       \
    }

#define G1_MFMA(q, A0, A1)                                                        \
    _Pragma("unroll")                                                             \
    for (int ni = 0; ni < 4; ++ni) {                                              \
        acc[2*(q)][ni]   = __builtin_amdgcn_mfma_f32_16x16x32_bf16(A0[0], bfr[ni][0], acc[2*(q)][ni], 0, 0, 0);   \
        acc[2*(q)][ni]   = __builtin_amdgcn_mfma_f32_16x16x32_bf16(A0[1], bfr[ni][1], acc[2*(q)][ni], 0, 0, 0);   \
        acc[2*(q)+1][ni] = __builtin_amdgcn_mfma_f32_16x16x32_bf16(A1[0], bfr[ni][0], acc[2*(q)+1][ni], 0, 0, 0); \
        acc[2*(q)+1][ni] = __builtin_amdgcn_mfma_f32_16x16x32_bf16(A1[1], bfr[ni][1], acc[2*(q)+1][ni], 0, 0, 0); \
    }

    // prologue: issue order must match steady state: Bh0(0),Bh1(0),Ah0(0),Ah1(0),Bh0(1),Bh1(1)
    stageB(0, 0, 2); stageB(1, 0, 3);
    stageA(0, 0, 0); stageA(1, 0, 1);
    stageB(0, 1, 6); stageB(1, 1, 7);
    asm volatile("s_waitcnt vmcnt(6)" ::: "memory");   // commit {Bh0,Bh1,Ah0}(0)
    __builtin_amdgcn_s_barrier();

#pragma unroll 2
    for (int kt = 0; kt < 16; ++kt) {
        const int p = kt & 1;
        const int ktA = (kt + 1) & 15;      // wraps at end: redundant but safe/deterministic
        const int ktB = (kt + 2) & 15;
        const int pA = ktA & 1;             // = p^1
        bf16x8 a0[2], a1[2];
        // ---- P0: read A j0,j1 + all B; stage Ah0(kt+1)
        G1_READA(0, p, a0, a1)
#pragma unroll
        for (int ni = 0; ni < 4; ++ni) {
            const u16* bb = smem + (p * 4 + 2 + bSlotHi) * SLOT + bRd + ni * 1024;
            bfr[ni][0] = *(const bf16x8*)&bb[c0];
            bfr[ni][1] = *(const bf16x8*)&bb[c1];
        }
        stageA(0, ktA, pA * 4);
        __builtin_amdgcn_s_barrier();
        asm volatile("s_waitcnt lgkmcnt(0)" ::: "memory");
        __builtin_amdgcn_sched_barrier(0);
        __builtin_amdgcn_s_setprio(1);
        G1_MFMA(0, a0, a1)
        __builtin_amdgcn_s_setprio(0);
        // ---- P1: read A j2,j3; stage Ah1(kt+1); vmcnt(8) commits Ah1(kt)
        G1_READA(1, p, a0, a1)
        stageA(1, ktA, pA * 4 + 1);
        asm volatile("s_waitcnt vmcnt(8)" ::: "memory");
        __builtin_amdgcn_s_barrier();
        asm volatile("s_waitcnt lgkmcnt(0)" ::: "memory");
        __builtin_amdgcn_sched_barrier(0);
        __builtin_amdgcn_s_setprio(1);
        G1_MFMA(1, a0, a1)
        __builtin_amdgcn_s_setprio(0);
        // ---- P2: read A j4,j5 (Ah1, committed @P1); stage Bh0(kt+2)
        G1_READA(2, p, a0, a1)
        stageB(0, ktB, p * 4 + 2);
        __builtin_amdgcn_s_barrier();
        asm volatile("s_waitcnt lgkmcnt(0)" ::: "memory");
        __builtin_amdgcn_sched_barrier(0);
        __builtin_amdgcn_s_setprio(1);
        G1_MFMA(2, a0, a1)
        __builtin_amdgcn_s_setprio(0);
        // ---- P3: read A j6,j7; stage Bh1(kt+2); vmcnt(6) commits {Bh0,Bh1,Ah0}(kt+1)
        G1_READA(3, p, a0, a1)
        stageB(1, ktB, p * 4 + 3);
        asm volatile("s_waitcnt vmcnt(6)" ::: "memory");
        __builtin_amdgcn_s_barrier();
        asm volatile("s_waitcnt lgkmcnt(0)" ::: "memory");
        __builtin_amdgcn_sched_barrier(0);
        __builtin_amdgcn_s_setprio(1);
        G1_MFMA(3, a0, a1)
        __builtin_amdgcn_s_setprio(0);
    }
#undef G1_READA
#undef G1_MFMA

    const int crow = (lane >> 4) * 4;
#pragma unroll
    for (int j = 0; j < 8; ++j) {
#pragma unroll
        for (int ni = 0; ni < 4; ++ni) {
            const int col = n0 + wc * 64 + ni * 16 + l15;
            const float bias = biascat[col];
#pragma unroll
            for (int r = 0; r < 4; ++r) {
                const int row = m0 + wr * 16 + j * 32 + crow + r;
                float v = acc[j][ni][r] + bias;
                v = (col < 2432) ? gelu_erf(v) : fmaxf(v, 0.f);  // gelu experts/shared/router, relu value
                h1[(size_t)row * NBIG + col] = f2bf(v);
            }
        }
    }
}

// ---------------- router softmax + value rtg ----------------

__global__ void k_router_value(const u16* __restrict__ h1,
                               const float* __restrict__ rw2, const float* __restrict__ rb2,
                               const float* __restrict__ vw2, const float* __restrict__ vb2,
                               float* __restrict__ probs_out, float* __restrict__ rtg_out) {
    __shared__ float rh[32][130];
    __shared__ float vh[32][130];
    __shared__ float w2[RH_DIM * E_NUM];
    __shared__ float vw[RH_DIM];
    const int tid = threadIdx.x;
    const int t0 = blockIdx.x * 32;
    for (int i = tid; i < RH_DIM * E_NUM; i += 256) w2[i] = rw2[i];
    if (tid < RH_DIM) vw[tid] = vw2[tid];
    {
        const int row = tid >> 3;
        const int c0 = (tid & 7) * 16;
        const u16* srcr = h1 + (size_t)(t0 + row) * NBIG + 2304 + c0;
        const u16* srcv = h1 + (size_t)(t0 + row) * NBIG + 2432 + c0;
        u16x8 a0 = *(const u16x8*)srcr;
        u16x8 a1 = *(const u16x8*)(srcr + 8);
        u16x8 b0 = *(const u16x8*)srcv;
        u16x8 b1 = *(const u16x8*)(srcv + 8);
#pragma unroll
        for (int j = 0; j < 8; ++j) {
            rh[row][c0 + j] = bf2f(a0[j]);
            rh[row][c0 + 8 + j] = bf2f(a1[j]);
            vh[row][c0 + j] = bf2f(b0[j]);
            vh[row][c0 + 8 + j] = bf2f(b1[j]);
        }
    }
    __syncthreads();
    const int tl = tid >> 3, a = tid & 7;
    float acc = rb2[a];
#pragma unroll 8
    for (int d = 0; d < RH_DIM; ++d) acc += rh[tl][d] * w2[d * E_NUM + a];
    float mx = acc;
    mx = fmaxf(mx, __shfl_xor(mx, 1));
    mx = fmaxf(mx, __shfl_xor(mx, 2));
    mx = fmaxf(mx, __shfl_xor(mx, 4));
    float ex = expf(acc - mx);
    float sm = ex;
    sm += __shfl_xor(sm, 1);
    sm += __shfl_xor(sm, 2);
    sm += __shfl_xor(sm, 4);
    probs_out[(size_t)(t0 + tl) * E_NUM + a] = ex / sm;
    float pv = 0.f;
#pragma unroll
    for (int j = 0; j < 16; ++j) pv += vh[tl][a * 16 + j] * vw[a * 16 + j];
    pv += __shfl_xor(pv, 1);
    pv += __shfl_xor(pv, 2);
    pv += __shfl_xor(pv, 4);
    if (a == 0) rtg_out[t0 + tl] = 1.f / (1.f + expf(-(pv + vb2[0])));
}

// ---------------- GEMM2: H1[Tx2304] @ W2T^T with per-expert prob fold -> weighted/moe ----------------

__launch_bounds__(256, 4)
__global__ void k_gemm2(const u16* __restrict__ h1, const u16* __restrict__ w2t,
                        const float* __restrict__ probs,
                        const float* __restrict__ eb2, const float* __restrict__ sb2,
                        float* __restrict__ moe_out, float* __restrict__ wgt_out) {
    __shared__ u16 As[2][64 * 64];
    __shared__ u16 Bs[2][32 * 64];
    __shared__ float plds[64 * E_NUM];
    const int tid = threadIdx.x;
    const int wid = tid >> 6;
    const int lane = tid & 63;
    const int m0 = blockIdx.x * 64;
    const int csrc = 8 * ((tid & 7) ^ ((tid >> 3) & 7));
    const int rxor = (lane & 7) * 8;
    const int lhi8 = (lane >> 4) * 8;
    const int crow = (lane >> 4) * 4;
    const int ccol = lane & 15;

    for (int i = tid; i < 64 * E_NUM; i += 256) plds[i] = probs[(size_t)m0 * E_NUM + i];

    f32x4 accE[2], accT[2], accS[2];
#pragma unroll
    for (int n = 0; n < 2; ++n) {
        accE[n] = (f32x4){0.f, 0.f, 0.f, 0.f};
        accT[n] = (f32x4){0.f, 0.f, 0.f, 0.f};
        accS[n] = (f32x4){0.f, 0.f, 0.f, 0.f};
    }

    auto stage = [&](int buf, int kt) {   // 3 gload_lds per thread
        const int k0 = kt * 64;
#pragma unroll
        for (int j = 0; j < 2; ++j)       // A: 64 rows, 2 rounds of 32
            gload_lds16(h1 + (size_t)(m0 + j * 32 + (tid >> 3)) * NBIG + k0 + csrc,
                        &As[buf][j * 2048 + wid * 512]);
        gload_lds16(w2t + (size_t)(tid >> 3) * K2 + k0 + csrc, &Bs[buf][wid * 512]);
    };

    stage(0, 0);
    __syncthreads();
    int cur = 0;
    for (int kt = 0; kt < 36; ++kt) {
        if (kt < 35) stage(cur ^ 1, kt + 1);
        const bool isExp = (kt < 32);
#pragma unroll
        for (int kk = 0; kk < 64; kk += 32) {
            bf16x8 av = *(const bf16x8*)&As[cur][(wid * 16 + (lane & 15)) * 64 + ((kk + lhi8) ^ rxor)];
            bf16x8 bv0 = *(const bf16x8*)&Bs[cur][((lane & 15)) * 64 + ((kk + lhi8) ^ rxor)];
            bf16x8 bv1 = *(const bf16x8*)&Bs[cur][(16 + (lane & 15)) * 64 + ((kk + lhi8) ^ rxor)];
            if (isExp) {
                accE[0] = __builtin_amdgcn_mfma_f32_16x16x32_bf16(av, bv0, accE[0], 0, 0, 0);
                accE[1] = __builtin_amdgcn_mfma_f32_16x16x32_bf16(av, bv1, accE[1], 0, 0, 0);
            } else {
                accS[0] = __builtin_amdgcn_mfma_f32_16x16x32_bf16(av, bv0, accS[0], 0, 0, 0);
                accS[1] = __builtin_amdgcn_mfma_f32_16x16x32_bf16(av, bv1, accS[1], 0, 0, 0);
            }
        }
        if (isExp && (kt & 3) == 3) {
            const int e = kt >> 2;
#pragma unroll
            for (int r = 0; r < 4; ++r) {
                const float p = plds[(wid * 16 + crow + r) * E_NUM + e];
#pragma unroll
                for (int n = 0; n < 2; ++n) {
                    accT[n][r] += p * accE[n][r];
                    accE[n][r] = 0.f;
                }
            }
        }
        __syncthreads();
        cur ^= 1;
    }

#pragma unroll
    for (int n = 0; n < 2; ++n) {
        const int aIdx = n * 16 + ccol;
#pragma unroll
        for (int r = 0; r < 4; ++r) {
            const int row = wid * 16 + crow + r;
            const int t = m0 + row;
            float wb = 0.f;
#pragma unroll
            for (int e = 0; e < E_NUM; ++e) wb += plds[row * E_NUM + e] * eb2[e * A_DIM + aIdx];
            const float w = accT[n][r] + wb;              // weighted_expert
            const float mo = w + accS[n][r] + sb2[aIdx];  // + shared_output
            wgt_out[(size_t)t * A_DIM + aIdx] = w;
            moe_out[(size_t)t * A_DIM + aIdx] = mo;
        }
    }
}

// ---------------- residual MLP + final combine ----------------

__global__ void k_final(const float* __restrict__ moe, const float* __restrict__ wgt,
                        const float* __restrict__ mw1, const float* __restrict__ mb1,
                        const float* __restrict__ mw2, const float* __restrict__ mb2,
                        const float* __restrict__ mask, float* __restrict__ outp) {
    __shared__ float w1[A_DIM * RH_DIM];
    __shared__ float w2[RH_DIM * A_DIM];
    __shared__ float mo[32][33];
    __shared__ float rh[32][128];
    const int tid = threadIdx.x;
    const int t0 = blockIdx.x * 32;
    for (int i = tid; i < A_DIM * RH_DIM; i += 1024) { w1[i] = mw1[i]; w2[i] = mw2[i]; }
    const int tl = tid >> 5, a = tid & 31;
    mo[tl][a] = moe[(size_t)(t0 + tl) * A_DIM + a];
    __syncthreads();
#pragma unroll
    for (int jj = 0; jj < 4; ++jj) {
        const int j = a * 4 + jj;
        float s = mb1[j];
#pragma unroll
        for (int aa = 0; aa < 32; ++aa) s += mo[tl][aa] * w1[aa * RH_DIM + j];
        rh[tl][j] = gelu_erf(s);
    }
    __syncthreads();
    float s = mb2[a];
#pragma unroll
    for (int j = 0; j < RH_DIM; ++j) s += rh[tl][j] * w2[j * A_DIM + a];
    const float res = wgt[(size_t)(t0 + tl) * A_DIM + a] + s;
    outp[(size_t)(t0 + tl) * A_DIM + a] = res * mask[t0 + tl];
}

// ---------------- launch ----------------

extern "C" void kernel_launch(void* const* d_in, const int* in_sizes, int n_in,
                              void* d_out, int out_size, void* d_ws, size_t ws_size,
                              hipStream_t stream) {
    const float* state = (const float*)d_in[0];
    const float* base  = (const float*)d_in[1];
    const float* mask  = (const float*)d_in[2];
    const float* sw1 = (const float*)d_in[3];
    const float* sb1 = (const float*)d_in[4];
    const float* sw2 = (const float*)d_in[5];
    const float* sb2 = (const float*)d_in[6];
    const float* ew1 = (const float*)d_in[7];
    const float* eb1 = (const float*)d_in[8];
    const float* ew2 = (const float*)d_in[9];
    const float* eb2 = (const float*)d_in[10];
    const float* rw1 = (const float*)d_in[11];
    const float* rb1 = (const float*)d_in[12];
    const float* rw2 = (const float*)d_in[13];
    const float* rb2 = (const float*)d_in[14];
    const float* mw1 = (const float*)d_in[15];
    const float* mb1 = (const float*)d_in[16];
    const float* mw2 = (const float*)d_in[17];
    const float* mb2 = (const float*)d_in[18];
    const float* vw1 = (const float*)d_in[19];
    const float* vb1 = (const float*)d_in[20];
    const float* vw2 = (const float*)d_in[21];
    const float* vb2 = (const float*)d_in[22];

    float* out_final = (float*)d_out;                 // [32768][32]
    float* out_cand  = out_final + 1048576;           // [32768][8][32]
    float* out_probs = out_final + 9437184;           // [32768][8]
    float* out_rtg   = out_final + 9699328;           // [32768]

    // adaptive chunking: largest chunk whose ws footprint fits (deterministic in ws_size)
    auto al = [](size_t b) { return (b + 255) & ~(size_t)255; };
    auto need = [&](size_t T) {
        return al((size_t)NBIG * H_DIM * 2) + al((size_t)A_DIM * K2 * 2) + al((size_t)NBIG * 4)
             + al(T * H_DIM * 2) + al(T * NBIG * 2) + 2 * al(T * A_DIM * 4);
    };
    size_t Tc = 8192;
    if (need(32768) <= ws_size)      Tc = 32768;
    else if (need(16384) <= ws_size) Tc = 16384;
    const int nchunk = (int)(T_TOT / Tc);

    char* ws = (char*)d_ws;
    size_t off = 0;
    auto take = [&](size_t b) { char* p = ws + off; off += (b + 255) & ~(size_t)255; return p; };
    u16*   wbf   = (u16*)take((size_t)NBIG * H_DIM * 2);
    u16*   w2t   = (u16*)take((size_t)A_DIM * K2 * 2);
    float* bias  = (float*)take((size_t)NBIG * 4);
    u16*   xb    = (u16*)take(Tc * H_DIM * 2);
    u16*   h1    = (u16*)take(Tc * NBIG * 2);
    float* moe   = (float*)take(Tc * A_DIM * 4);
    float* wgt   = (float*)take(Tc * A_DIM * 4);
    (void)in_sizes; (void)n_in; (void)out_size;

    k_pack_w<<<(NBIG * H_DIM) / 256, 256, 0, stream>>>(ew1, sw1, rw1, vw1, eb1, sb1, rb1, vb1, wbf, bias);
    k_pack_w2t<<<(A_DIM * K2) / 256, 256, 0, stream>>>(ew2, sw2, w2t);
    k_cand<<<(T_TOT * E_NUM * A_DIM) / 256, 256, 0, stream>>>(base, out_cand);

    for (int c = 0; c < nchunk; ++c) {
        const size_t tb = (size_t)c * Tc;
        k_convert_x<<<(int)(Tc * H_DIM / 4 / 256), 256, 0, stream>>>(state + tb * H_DIM, xb, (int)(Tc * H_DIM / 4));
        k_gemm1<<<10 * (int)(Tc / 256), 512, 0, stream>>>(xb, wbf, bias, h1);
        k_router_value<<<(int)(Tc / 32), 256, 0, stream>>>(h1, rw2, rb2, vw2, vb2,
                                                           out_probs + tb * E_NUM, out_rtg + tb);
        k_gemm2<<<(int)(Tc / 64), 256, 0, stream>>>(h1, w2t, out_probs + tb * E_NUM, eb2, sb2, moe, wgt);
        k_final<<<(int)(Tc / 32), 1024, 0, stream>>>(moe, wgt, mw1, mb1, mw2, mb2, mask + tb, out_final + tb * A_DIM);
    }
}

// Round 8
// 332.293 us; speedup vs baseline: 1.3487x; 1.1899x over previous
//
#include <hip/hip_runtime.h>
#include <stdint.h>

// Problem dims
#define T_TOT 32768   // B*S
#define H_DIM 1024
#define A_DIM 32
#define E_NUM 8
#define ED_DIM 256
#define RH_DIM 128
#define NBIG 2560     // 8*256 experts + 256 shared + 128 router + 128 value
#define K2 2304       // 8*256 + 256 (expert+shared h1 -> action)

typedef float f32x4 __attribute__((ext_vector_type(4)));
typedef short bf16x8 __attribute__((ext_vector_type(8)));
typedef unsigned short u16;
typedef u16 u16x8 __attribute__((ext_vector_type(8)));

typedef uint32_t __attribute__((address_space(1))) as1_u32;
typedef uint32_t __attribute__((address_space(3))) as3_u32;

__device__ __forceinline__ u16 f2bf(float f) {
    union { float f; uint32_t u; } v; v.f = f;
    return (u16)((v.u + 0x7FFFu + ((v.u >> 16) & 1u)) >> 16);  // RNE
}
__device__ __forceinline__ float bf2f(u16 h) {
    union { uint32_t u; float f; } v; v.u = ((uint32_t)h) << 16;
    return v.f;
}
// Branchless erf-GELU via Abramowitz-Stegun 7.1.26 (|erf err| <= 1.5e-7).
// ~16 VALU ops, no divergence — replaces __ocml_erf_f32 (~40-80 ops w/ branches),
// which made the gemm1 epilogue VALU-bound (round-7 post-mortem).
__device__ __forceinline__ float gelu_fast(float x) {
    const float s = x * 0.70710678118654752f;
    const float a = fabsf(s);
    const float t = __builtin_amdgcn_rcpf(fmaf(0.3275911f, a, 1.0f));
    const float e = __expf(-a * a);
    float p = fmaf(1.061405429f, t, -1.453152027f);
    p = fmaf(p, t, 1.421413741f);
    p = fmaf(p, t, -0.284496736f);
    p = fmaf(p, t, 0.254829592f);
    p = p * t;
    const float erfa = fmaf(-p, e, 1.0f);     // erf(|s|), always >= 0
    const float erfs = copysignf(erfa, s);
    return 0.5f * x * (1.0f + erfs);
}
__device__ __forceinline__ void gload_lds16(const void* g, void* lds) {
    __builtin_amdgcn_global_load_lds((const as1_u32*)(uintptr_t)g,
                                     (as3_u32*)(uintptr_t)lds, 16, 0, 0);
}

// ---------------- setup kernels ----------------

__global__ void k_convert_x(const float* __restrict__ x, u16* __restrict__ xb, int n4) {
    int i = blockIdx.x * blockDim.x + threadIdx.x;
    if (i >= n4) return;
    float4 v = ((const float4*)x)[i];
    ushort4 o;
    o.x = f2bf(v.x); o.y = f2bf(v.y); o.z = f2bf(v.z); o.w = f2bf(v.w);
    ((ushort4*)xb)[i] = o;
}

// pack big W^T [NBIG][K=1024] bf16 + concatenated bias (fp32)
__global__ void k_pack_w(const float* __restrict__ ew1, const float* __restrict__ sw1,
                         const float* __restrict__ rw1, const float* __restrict__ vw1,
                         const float* __restrict__ eb1, const float* __restrict__ sb1,
                         const float* __restrict__ rb1, const float* __restrict__ vb1,
                         u16* __restrict__ wbf, float* __restrict__ biascat) {
    int t = blockIdx.x * blockDim.x + threadIdx.x;
    if (t >= NBIG * H_DIM) return;
    int n = t >> 10, k = t & 1023;
    float v;
    if (n < 2048)      v = ew1[(size_t)(((n >> 8) * H_DIM) + k) * ED_DIM + (n & 255)];
    else if (n < 2304) v = sw1[(size_t)k * ED_DIM + (n - 2048)];
    else if (n < 2432) v = rw1[(size_t)k * RH_DIM + (n - 2304)];
    else               v = vw1[(size_t)k * RH_DIM + (n - 2432)];
    wbf[t] = f2bf(v);
    if (k == 0) {
        float b;
        if (n < 2048)      b = eb1[(n >> 8) * ED_DIM + (n & 255)];
        else if (n < 2304) b = sb1[n - 2048];
        else if (n < 2432) b = rb1[n - 2304];
        else               b = vb1[n - 2432];
        biascat[n] = b;
    }
}

// pack second-layer weights transposed: W2T [32][2304] bf16 (expert | shared)
__global__ void k_pack_w2t(const float* __restrict__ ew2, const float* __restrict__ sw2,
                           u16* __restrict__ w2t) {
    int t = blockIdx.x * blockDim.x + threadIdx.x;
    if (t >= A_DIM * K2) return;
    int a = t / K2, d = t - a * K2;
    float v = (d < 2048) ? ew2[(size_t)d * A_DIM + a] : sw2[(size_t)(d - 2048) * A_DIM + a];
    w2t[t] = f2bf(v);
}

__global__ void k_cand(const float* __restrict__ base, float* __restrict__ outp) {
    int i = blockIdx.x * blockDim.x + threadIdx.x;
    if (i >= T_TOT * E_NUM * A_DIM) return;
    int a = i & 31, e = (i >> 5) & 7, t = i >> 8;
    outp[i] = base[(size_t)t * A_DIM + a] * (0.8f + 0.4f * (float)e / 7.0f);
}

// ---------------- GEMM1: X[Tx1024] @ Wbig -> H1[Tx2560] ----------------
// m201-style schedule (T2+T3+T4+T5) as a half-tile ring (see round-7 notes):
//   BM=BN=256, BK=64, 512 thr / 8 waves (2M x 4N), per-wave out 128x64.
//   LDS = ring of 8 slots x 16KB = 128 KB. 4 phases/K-tile, 16 MFMA each.
//   Stage plan per tile t: P0->Ah0(t+1), P1->Ah1(t+1), P2->Bh0(t+2), P3->Bh1(t+2).
//   vmcnt(8)@P1 / vmcnt(6)@P3 only — never 0 in-loop; 3 halves in flight.
//   T2 swizzle: LDS slot s of row r holds global slot s^(r&7); read XORs back.

#define SLOT 8192   // u16 per 16KB slot (128 rows x 64)

__launch_bounds__(512, 2)
__global__ void k_gemm1(const u16* __restrict__ xb, const u16* __restrict__ wbf,
                        const float* __restrict__ biascat, u16* __restrict__ h1) {
    __shared__ u16 smem[8 * SLOT];   // 128 KB
    const int tid = threadIdx.x;
    const int wid = tid >> 6;
    const int lane = tid & 63;
    // XCD-aware bijective swizzle (gridDim.x divisible by 8)
    const int lin = blockIdx.x;
    const int swz = (lin & 7) * ((int)gridDim.x >> 3) + (lin >> 3);
    const int bx = swz % 10;            // n-tile (NBIG/256 = 10)
    const int by = swz / 10;            // m-tile
    const int m0 = by * 256, n0 = bx * 256;
    const int wr = wid >> 2;            // 0..1 (m group)
    const int wc = wid & 3;             // 0..3 (n quarter)
    // staging addresses
    const int srow = tid >> 3;                              // 0..63
    const int cs = 8 * ((tid & 7) ^ (srow & 7));            // pre-swizzled col slot
    // read addresses
    const int l15 = lane & 15;
    const int rsw = (lane & 7) * 8;                         // read-side XOR
    const int lh8 = (lane >> 4) * 8;
    const int c0 = lh8 ^ rsw;                               // kk=0 col
    const int c1 = (32 + lh8) ^ rsw;                        // kk=1 col
    const int aRd = (wr * 16 + l15) * 64;                   // + (j&3)*2048 per frag
    const int bRd = ((wc & 1) * 64 + l15) * 64;             // + ni*1024 per frag
    const int bSlotHi = wc >> 1;                            // which B half this wave reads

    f32x4 acc[8][4];
#pragma unroll
    for (int j = 0; j < 8; ++j)
#pragma unroll
        for (int n = 0; n < 4; ++n) acc[j][n] = (f32x4){0.f, 0.f, 0.f, 0.f};

    auto stageA = [&](int h, int kt, int s) {   // 2 gload_lds
        const u16* src = xb + (size_t)(m0 + h * 128 + srow) * H_DIM + kt * 64 + cs;
        u16* dst = smem + s * SLOT + wid * 512;
        gload_lds16(src, dst);
        gload_lds16(src + (size_t)64 * H_DIM, dst + 4096);
    };
    auto stageB = [&](int h, int kt, int s) {
        const u16* src = wbf + (size_t)(n0 + h * 128 + srow) * H_DIM + kt * 64 + cs;
        u16* dst = smem + s * SLOT + wid * 512;
        gload_lds16(src, dst);
        gload_lds16(src + (size_t)64 * H_DIM, dst + 4096);
    };

    bf16x8 bfr[4][2];

#define G1_READA(q, P, A0, A1)                                                    \
    {                                                                             \
        const u16* ab0 = smem + ((P) * 4 + ((q) >> 1)) * SLOT + aRd + (((2*(q)) & 3) * 2048);     \
        const u16* ab1 = smem + ((P) * 4 + ((q) >> 1)) * SLOT + aRd + (((2*(q)+1) & 3) * 2048);   \
        A0[0] = *(const bf16x8*)&ab0[c0]; A0[1] = *(const bf16x8*)&ab0[c1];       \
        A1[0] = *(const bf16x8*)&ab1[c0]; A1[1] = *(const bf16x8*)&ab1[c1];       \
    }

#define G1_MFMA(q, A0, A1)                                                        \
    _Pragma("unroll")                                                             \
    for (int ni = 0; ni < 4; ++ni) {                                              \
        acc[2*(q)][ni]   = __builtin_amdgcn_mfma_f32_16x16x32_bf16(A0[0], bfr[ni][0], acc[2*(q)][ni], 0, 0, 0);   \
        acc[2*(q)][ni]   = __builtin_amdgcn_mfma_f32_16x16x32_bf16(A0[1], bfr[ni][1], acc[2*(q)][ni], 0, 0, 0);   \
        acc[2*(q)+1][ni] = __builtin_amdgcn_mfma_f32_16x16x32_bf16(A1[0], bfr[ni][0], acc[2*(q)+1][ni], 0, 0, 0); \
        acc[2*(q)+1][ni] = __builtin_amdgcn_mfma_f32_16x16x32_bf16(A1[1], bfr[ni][1], acc[2*(q)+1][ni], 0, 0, 0); \
    }

    // prologue: issue order must match steady state: Bh0(0),Bh1(0),Ah0(0),Ah1(0),Bh0(1),Bh1(1)
    stageB(0, 0, 2); stageB(1, 0, 3);
    stageA(0, 0, 0); stageA(1, 0, 1);
    stageB(0, 1, 6); stageB(1, 1, 7);
    asm volatile("s_waitcnt vmcnt(6)" ::: "memory");   // commit {Bh0,Bh1,Ah0}(0)
    __builtin_amdgcn_s_barrier();

#pragma unroll 2
    for (int kt = 0; kt < 16; ++kt) {
        const int p = kt & 1;
        const int ktA = (kt + 1) & 15;      // wraps at end: redundant but safe/deterministic
        const int ktB = (kt + 2) & 15;
        const int pA = ktA & 1;             // = p^1
        bf16x8 a0[2], a1[2];
        // ---- P0: read A j0,j1 + all B; stage Ah0(kt+1)
        G1_READA(0, p, a0, a1)
#pragma unroll
        for (int ni = 0; ni < 4; ++ni) {
            const u16* bb = smem + (p * 4 + 2 + bSlotHi) * SLOT + bRd + ni * 1024;
            bfr[ni][0] = *(const bf16x8*)&bb[c0];
            bfr[ni][1] = *(const bf16x8*)&bb[c1];
        }
        stageA(0, ktA, pA * 4);
        __builtin_amdgcn_s_barrier();
        asm volatile("s_waitcnt lgkmcnt(0)" ::: "memory");
        __builtin_amdgcn_sched_barrier(0);
        __builtin_amdgcn_s_setprio(1);
        G1_MFMA(0, a0, a1)
        __builtin_amdgcn_s_setprio(0);
        // ---- P1: read A j2,j3; stage Ah1(kt+1); vmcnt(8) commits Ah1(kt)
        G1_READA(1, p, a0, a1)
        stageA(1, ktA, pA * 4 + 1);
        asm volatile("s_waitcnt vmcnt(8)" ::: "memory");
        __builtin_amdgcn_s_barrier();
        asm volatile("s_waitcnt lgkmcnt(0)" ::: "memory");
        __builtin_amdgcn_sched_barrier(0);
        __builtin_amdgcn_s_setprio(1);
        G1_MFMA(1, a0, a1)
        __builtin_amdgcn_s_setprio(0);
        // ---- P2: read A j4,j5 (Ah1, committed @P1); stage Bh0(kt+2)
        G1_READA(2, p, a0, a1)
        stageB(0, ktB, p * 4 + 2);
        __builtin_amdgcn_s_barrier();
        asm volatile("s_waitcnt lgkmcnt(0)" ::: "memory");
        __builtin_amdgcn_sched_barrier(0);
        __builtin_amdgcn_s_setprio(1);
        G1_MFMA(2, a0, a1)
        __builtin_amdgcn_s_setprio(0);
        // ---- P3: read A j6,j7; stage Bh1(kt+2); vmcnt(6) commits {Bh0,Bh1,Ah0}(kt+1)
        G1_READA(3, p, a0, a1)
        stageB(1, ktB, p * 4 + 3);
        asm volatile("s_waitcnt vmcnt(6)" ::: "memory");
        __builtin_amdgcn_s_barrier();
        asm volatile("s_waitcnt lgkmcnt(0)" ::: "memory");
        __builtin_amdgcn_sched_barrier(0);
        __builtin_amdgcn_s_setprio(1);
        G1_MFMA(3, a0, a1)
        __builtin_amdgcn_s_setprio(0);
    }
#undef G1_READA
#undef G1_MFMA

    const int crow = (lane >> 4) * 4;
#pragma unroll
    for (int j = 0; j < 8; ++j) {
#pragma unroll
        for (int ni = 0; ni < 4; ++ni) {
            const int col = n0 + wc * 64 + ni * 16 + l15;
            const float bias = biascat[col];
#pragma unroll
            for (int r = 0; r < 4; ++r) {
                const int row = m0 + wr * 16 + j * 32 + crow + r;
                float v = acc[j][ni][r] + bias;
                v = (col < 2432) ? gelu_fast(v) : fmaxf(v, 0.f);  // gelu experts/shared/router, relu value
                h1[(size_t)row * NBIG + col] = f2bf(v);
            }
        }
    }
}

// ---------------- router softmax + value rtg ----------------

__global__ void k_router_value(const u16* __restrict__ h1,
                               const float* __restrict__ rw2, const float* __restrict__ rb2,
                               const float* __restrict__ vw2, const float* __restrict__ vb2,
                               float* __restrict__ probs_out, float* __restrict__ rtg_out) {
    __shared__ float rh[32][130];
    __shared__ float vh[32][130];
    __shared__ float w2[RH_DIM * E_NUM];
    __shared__ float vw[RH_DIM];
    const int tid = threadIdx.x;
    const int t0 = blockIdx.x * 32;
    for (int i = tid; i < RH_DIM * E_NUM; i += 256) w2[i] = rw2[i];
    if (tid < RH_DIM) vw[tid] = vw2[tid];
    {
        const int row = tid >> 3;
        const int c0 = (tid & 7) * 16;
        const u16* srcr = h1 + (size_t)(t0 + row) * NBIG + 2304 + c0;
        const u16* srcv = h1 + (size_t)(t0 + row) * NBIG + 2432 + c0;
        u16x8 a0 = *(const u16x8*)srcr;
        u16x8 a1 = *(const u16x8*)(srcr + 8);
        u16x8 b0 = *(const u16x8*)srcv;
        u16x8 b1 = *(const u16x8*)(srcv + 8);
#pragma unroll
        for (int j = 0; j < 8; ++j) {
            rh[row][c0 + j] = bf2f(a0[j]);
            rh[row][c0 + 8 + j] = bf2f(a1[j]);
            vh[row][c0 + j] = bf2f(b0[j]);
            vh[row][c0 + 8 + j] = bf2f(b1[j]);
        }
    }
    __syncthreads();
    const int tl = tid >> 3, a = tid & 7;
    float acc = rb2[a];
#pragma unroll 8
    for (int d = 0; d < RH_DIM; ++d) acc += rh[tl][d] * w2[d * E_NUM + a];
    float mx = acc;
    mx = fmaxf(mx, __shfl_xor(mx, 1));
    mx = fmaxf(mx, __shfl_xor(mx, 2));
    mx = fmaxf(mx, __shfl_xor(mx, 4));
    float ex = expf(acc - mx);
    float sm = ex;
    sm += __shfl_xor(sm, 1);
    sm += __shfl_xor(sm, 2);
    sm += __shfl_xor(sm, 4);
    probs_out[(size_t)(t0 + tl) * E_NUM + a] = ex / sm;
    float pv = 0.f;
#pragma unroll
    for (int j = 0; j < 16; ++j) pv += vh[tl][a * 16 + j] * vw[a * 16 + j];
    pv += __shfl_xor(pv, 1);
    pv += __shfl_xor(pv, 2);
    pv += __shfl_xor(pv, 4);
    if (a == 0) rtg_out[t0 + tl] = 1.f / (1.f + expf(-(pv + vb2[0])));
}

// ---------------- GEMM2: H1[Tx2304] @ W2T^T with per-expert prob fold -> weighted/moe ----------------

__launch_bounds__(256, 4)
__global__ void k_gemm2(const u16* __restrict__ h1, const u16* __restrict__ w2t,
                        const float* __restrict__ probs,
                        const float* __restrict__ eb2, const float* __restrict__ sb2,
                        float* __restrict__ moe_out, float* __restrict__ wgt_out) {
    __shared__ u16 As[2][64 * 64];
    __shared__ u16 Bs[2][32 * 64];
    __shared__ float plds[64 * E_NUM];
    const int tid = threadIdx.x;
    const int wid = tid >> 6;
    const int lane = tid & 63;
    const int m0 = blockIdx.x * 64;
    const int csrc = 8 * ((tid & 7) ^ ((tid >> 3) & 7));
    const int rxor = (lane & 7) * 8;
    const int lhi8 = (lane >> 4) * 8;
    const int crow = (lane >> 4) * 4;
    const int ccol = lane & 15;

    for (int i = tid; i < 64 * E_NUM; i += 256) plds[i] = probs[(size_t)m0 * E_NUM + i];

    f32x4 accE[2], accT[2], accS[2];
#pragma unroll
    for (int n = 0; n < 2; ++n) {
        accE[n] = (f32x4){0.f, 0.f, 0.f, 0.f};
        accT[n] = (f32x4){0.f, 0.f, 0.f, 0.f};
        accS[n] = (f32x4){0.f, 0.f, 0.f, 0.f};
    }

    auto stage = [&](int buf, int kt) {   // 3 gload_lds per thread
        const int k0 = kt * 64;
#pragma unroll
        for (int j = 0; j < 2; ++j)       // A: 64 rows, 2 rounds of 32
            gload_lds16(h1 + (size_t)(m0 + j * 32 + (tid >> 3)) * NBIG + k0 + csrc,
                        &As[buf][j * 2048 + wid * 512]);
        gload_lds16(w2t + (size_t)(tid >> 3) * K2 + k0 + csrc, &Bs[buf][wid * 512]);
    };

    stage(0, 0);
    __syncthreads();
    int cur = 0;
    for (int kt = 0; kt < 36; ++kt) {
        if (kt < 35) stage(cur ^ 1, kt + 1);
        const bool isExp = (kt < 32);
#pragma unroll
        for (int kk = 0; kk < 64; kk += 32) {
            bf16x8 av = *(const bf16x8*)&As[cur][(wid * 16 + (lane & 15)) * 64 + ((kk + lhi8) ^ rxor)];
            bf16x8 bv0 = *(const bf16x8*)&Bs[cur][((lane & 15)) * 64 + ((kk + lhi8) ^ rxor)];
            bf16x8 bv1 = *(const bf16x8*)&Bs[cur][(16 + (lane & 15)) * 64 + ((kk + lhi8) ^ rxor)];
            if (isExp) {
                accE[0] = __builtin_amdgcn_mfma_f32_16x16x32_bf16(av, bv0, accE[0], 0, 0, 0);
                accE[1] = __builtin_amdgcn_mfma_f32_16x16x32_bf16(av, bv1, accE[1], 0, 0, 0);
            } else {
                accS[0] = __builtin_amdgcn_mfma_f32_16x16x32_bf16(av, bv0, accS[0], 0, 0, 0);
                accS[1] = __builtin_amdgcn_mfma_f32_16x16x32_bf16(av, bv1, accS[1], 0, 0, 0);
            }
        }
        if (isExp && (kt & 3) == 3) {
            const int e = kt >> 2;
#pragma unroll
            for (int r = 0; r < 4; ++r) {
                const float p = plds[(wid * 16 + crow + r) * E_NUM + e];
#pragma unroll
                for (int n = 0; n < 2; ++n) {
                    accT[n][r] += p * accE[n][r];
                    accE[n][r] = 0.f;
                }
            }
        }
        __syncthreads();
        cur ^= 1;
    }

#pragma unroll
    for (int n = 0; n < 2; ++n) {
        const int aIdx = n * 16 + ccol;
#pragma unroll
        for (int r = 0; r < 4; ++r) {
            const int row = wid * 16 + crow + r;
            const int t = m0 + row;
            float wb = 0.f;
#pragma unroll
            for (int e = 0; e < E_NUM; ++e) wb += plds[row * E_NUM + e] * eb2[e * A_DIM + aIdx];
            const float w = accT[n][r] + wb;              // weighted_expert
            const float mo = w + accS[n][r] + sb2[aIdx];  // + shared_output
            wgt_out[(size_t)t * A_DIM + aIdx] = w;
            moe_out[(size_t)t * A_DIM + aIdx] = mo;
        }
    }
}

// ---------------- residual MLP + final combine ----------------

__global__ void k_final(const float* __restrict__ moe, const float* __restrict__ wgt,
                        const float* __restrict__ mw1, const float* __restrict__ mb1,
                        const float* __restrict__ mw2, const float* __restrict__ mb2,
                        const float* __restrict__ mask, float* __restrict__ outp) {
    __shared__ float w1[A_DIM * RH_DIM];
    __shared__ float w2[RH_DIM * A_DIM];
    __shared__ float mo[32][33];
    __shared__ float rh[32][128];
    const int tid = threadIdx.x;
    const int t0 = blockIdx.x * 32;
    for (int i = tid; i < A_DIM * RH_DIM; i += 1024) { w1[i] = mw1[i]; w2[i] = mw2[i]; }
    const int tl = tid >> 5, a = tid & 31;
    mo[tl][a] = moe[(size_t)(t0 + tl) * A_DIM + a];
    __syncthreads();
#pragma unroll
    for (int jj = 0; jj < 4; ++jj) {
        const int j = a * 4 + jj;
        float s = mb1[j];
#pragma unroll
        for (int aa = 0; aa < 32; ++aa) s += mo[tl][aa] * w1[aa * RH_DIM + j];
        rh[tl][j] = gelu_fast(s);
    }
    __syncthreads();
    float s = mb2[a];
#pragma unroll
    for (int j = 0; j < RH_DIM; ++j) s += rh[tl][j] * w2[j * A_DIM + a];
    const float res = wgt[(size_t)(t0 + tl) * A_DIM + a] + s;
    outp[(size_t)(t0 + tl) * A_DIM + a] = res * mask[t0 + tl];
}

// ---------------- launch ----------------

extern "C" void kernel_launch(void* const* d_in, const int* in_sizes, int n_in,
                              void* d_out, int out_size, void* d_ws, size_t ws_size,
                              hipStream_t stream) {
    const float* state = (const float*)d_in[0];
    const float* base  = (const float*)d_in[1];
    const float* mask  = (const float*)d_in[2];
    const float* sw1 = (const float*)d_in[3];
    const float* sb1 = (const float*)d_in[4];
    const float* sw2 = (const float*)d_in[5];
    const float* sb2 = (const float*)d_in[6];
    const float* ew1 = (const float*)d_in[7];
    const float* eb1 = (const float*)d_in[8];
    const float* ew2 = (const float*)d_in[9];
    const float* eb2 = (const float*)d_in[10];
    const float* rw1 = (const float*)d_in[11];
    const float* rb1 = (const float*)d_in[12];
    const float* rw2 = (const float*)d_in[13];
    const float* rb2 = (const float*)d_in[14];
    const float* mw1 = (const float*)d_in[15];
    const float* mb1 = (const float*)d_in[16];
    const float* mw2 = (const float*)d_in[17];
    const float* mb2 = (const float*)d_in[18];
    const float* vw1 = (const float*)d_in[19];
    const float* vb1 = (const float*)d_in[20];
    const float* vw2 = (const float*)d_in[21];
    const float* vb2 = (const float*)d_in[22];

    float* out_final = (float*)d_out;                 // [32768][32]
    float* out_cand  = out_final + 1048576;           // [32768][8][32]
    float* out_probs = out_final + 9437184;           // [32768][8]
    float* out_rtg   = out_final + 9699328;           // [32768]

    // adaptive chunking: largest chunk whose ws footprint fits (deterministic in ws_size)
    auto al = [](size_t b) { return (b + 255) & ~(size_t)255; };
    auto need = [&](size_t T) {
        return al((size_t)NBIG * H_DIM * 2) + al((size_t)A_DIM * K2 * 2) + al((size_t)NBIG * 4)
             + al(T * H_DIM * 2) + al(T * NBIG * 2) + 2 * al(T * A_DIM * 4);
    };
    size_t Tc = 8192;
    if (need(32768) <= ws_size)      Tc = 32768;
    else if (need(16384) <= ws_size) Tc = 16384;
    const int nchunk = (int)(T_TOT / Tc);

    char* ws = (char*)d_ws;
    size_t off = 0;
    auto take = [&](size_t b) { char* p = ws + off; off += (b + 255) & ~(size_t)255; return p; };
    u16*   wbf   = (u16*)take((size_t)NBIG * H_DIM * 2);
    u16*   w2t   = (u16*)take((size_t)A_DIM * K2 * 2);
    float* bias  = (float*)take((size_t)NBIG * 4);
    u16*   xb    = (u16*)take(Tc * H_DIM * 2);
    u16*   h1    = (u16*)take(Tc * NBIG * 2);
    float* moe   = (float*)take(Tc * A_DIM * 4);
    float* wgt   = (float*)take(Tc * A_DIM * 4);
    (void)in_sizes; (void)n_in; (void)out_size;

    k_pack_w<<<(NBIG * H_DIM) / 256, 256, 0, stream>>>(ew1, sw1, rw1, vw1, eb1, sb1, rb1, vb1, wbf, bias);
    k_pack_w2t<<<(A_DIM * K2) / 256, 256, 0, stream>>>(ew2, sw2, w2t);
    k_cand<<<(T_TOT * E_NUM * A_DIM) / 256, 256, 0, stream>>>(base, out_cand);

    for (int c = 0; c < nchunk; ++c) {
        const size_t tb = (size_t)c * Tc;
        k_convert_x<<<(int)(Tc * H_DIM / 4 / 256), 256, 0, stream>>>(state + tb * H_DIM, xb, (int)(Tc * H_DIM / 4));
        k_gemm1<<<10 * (int)(Tc / 256), 512, 0, stream>>>(xb, wbf, bias, h1);
        k_router_value<<<(int)(Tc / 32), 256, 0, stream>>>(h1, rw2, rb2, vw2, vb2,
                                                           out_probs + tb * E_NUM, out_rtg + tb);
        k_gemm2<<<(int)(Tc / 64), 256, 0, stream>>>(h1, w2t, out_probs + tb * E_NUM, eb2, sb2, moe, wgt);
        k_final<<<(int)(Tc / 32), 1024, 0, stream>>>(moe, wgt, mw1, mb1, mw2, mb2, mask + tb, out_final + tb * A_DIM);
    }
}

// Round 9
// 326.524 us; speedup vs baseline: 1.3725x; 1.0177x over previous
//
#include <hip/hip_runtime.h>
#include <stdint.h>

// Problem dims
#define T_TOT 32768   // B*S
#define H_DIM 1024
#define A_DIM 32
#define E_NUM 8
#define ED_DIM 256
#define RH_DIM 128
#define NBIG 2560     // 8*256 experts + 256 shared + 128 router + 128 value
#define K2 2304       // 8*256 + 256 (expert+shared h1 -> action)

typedef float f32x4 __attribute__((ext_vector_type(4)));
typedef short bf16x8 __attribute__((ext_vector_type(8)));
typedef unsigned short u16;
typedef u16 u16x8 __attribute__((ext_vector_type(8)));

typedef uint32_t __attribute__((address_space(1))) as1_u32;
typedef uint32_t __attribute__((address_space(3))) as3_u32;

__device__ __forceinline__ u16 f2bf(float f) {
    union { float f; uint32_t u; } v; v.f = f;
    return (u16)((v.u + 0x7FFFu + ((v.u >> 16) & 1u)) >> 16);  // RNE
}
__device__ __forceinline__ float bf2f(u16 h) {
    union { uint32_t u; float f; } v; v.u = ((uint32_t)h) << 16;
    return v.f;
}
// Branchless erf-GELU via Abramowitz-Stegun 7.1.26 (|erf err| <= 1.5e-7).
__device__ __forceinline__ float gelu_fast(float x) {
    const float s = x * 0.70710678118654752f;
    const float a = fabsf(s);
    const float t = __builtin_amdgcn_rcpf(fmaf(0.3275911f, a, 1.0f));
    const float e = __expf(-a * a);
    float p = fmaf(1.061405429f, t, -1.453152027f);
    p = fmaf(p, t, 1.421413741f);
    p = fmaf(p, t, -0.284496736f);
    p = fmaf(p, t, 0.254829592f);
    p = p * t;
    const float erfa = fmaf(-p, e, 1.0f);
    const float erfs = copysignf(erfa, s);
    return 0.5f * x * (1.0f + erfs);
}
__device__ __forceinline__ void gload_lds16(const void* g, void* lds) {
    __builtin_amdgcn_global_load_lds((const as1_u32*)(uintptr_t)g,
                                     (as3_u32*)(uintptr_t)lds, 16, 0, 0);
}

// ---------------- merged setup kernel (pack_w | pack_w2t | w1b | w2b | cand | convert) ----------------

#define SW_N0 (NBIG * H_DIM)            // pack_w
#define SW_N1 (SW_N0 + A_DIM * K2)      // pack_w2t
#define SW_N2 (SW_N1 + 4096)            // w1b = bf16(mw1) [32][128]
#define SW_N3 (SW_N2 + 4096)            // w2b = bf16(mw2^T) [32][128]
#define SW_N4 (SW_N3 + T_TOT * E_NUM * A_DIM)  // cand

__global__ void k_setup(const float* __restrict__ ew1, const float* __restrict__ sw1,
                        const float* __restrict__ rw1, const float* __restrict__ vw1,
                        const float* __restrict__ eb1, const float* __restrict__ sb1,
                        const float* __restrict__ rb1, const float* __restrict__ vb1,
                        const float* __restrict__ ew2, const float* __restrict__ sw2,
                        const float* __restrict__ mw1, const float* __restrict__ mw2,
                        const float* __restrict__ base, const float* __restrict__ state,
                        u16* __restrict__ wbf, float* __restrict__ biascat,
                        u16* __restrict__ w2t, u16* __restrict__ w1b, u16* __restrict__ w2b,
                        float* __restrict__ cand_out, u16* __restrict__ xb, int nconv4) {
    int i = blockIdx.x * blockDim.x + threadIdx.x;
    if (i < SW_N0) {
        int n = i >> 10, k = i & 1023;
        float v;
        if (n < 2048)      v = ew1[(size_t)(((n >> 8) * H_DIM) + k) * ED_DIM + (n & 255)];
        else if (n < 2304) v = sw1[(size_t)k * ED_DIM + (n - 2048)];
        else if (n < 2432) v = rw1[(size_t)k * RH_DIM + (n - 2304)];
        else               v = vw1[(size_t)k * RH_DIM + (n - 2432)];
        wbf[i] = f2bf(v);
        if (k == 0) {
            float b;
            if (n < 2048)      b = eb1[(n >> 8) * ED_DIM + (n & 255)];
            else if (n < 2304) b = sb1[n - 2048];
            else if (n < 2432) b = rb1[n - 2304];
            else               b = vb1[n - 2432];
            biascat[n] = b;
        }
    } else if (i < SW_N1) {
        int t = i - SW_N0;
        int a = t / K2, d = t - a * K2;
        float v = (d < 2048) ? ew2[(size_t)d * A_DIM + a] : sw2[(size_t)(d - 2048) * A_DIM + a];
        w2t[t] = f2bf(v);
    } else if (i < SW_N2) {
        int t = i - SW_N1;                       // mw1 [32][128] straight
        w1b[t] = f2bf(mw1[t]);
    } else if (i < SW_N3) {
        int t = i - SW_N2;                       // w2b[c][j] = mw2[j][c]  (transposed)
        int c = t >> 7, j = t & 127;
        w2b[t] = f2bf(mw2[(size_t)j * A_DIM + c]);
    } else if (i < SW_N4) {
        int t = i - SW_N3;
        int a = t & 31, e = (t >> 5) & 7, tt = t >> 8;
        cand_out[t] = base[(size_t)tt * A_DIM + a] * (0.8f + 0.4f * (float)e / 7.0f);
    } else if (i < SW_N4 + nconv4) {
        int t = i - SW_N4;
        float4 v = ((const float4*)state)[t];
        ushort4 o;
        o.x = f2bf(v.x); o.y = f2bf(v.y); o.z = f2bf(v.z); o.w = f2bf(v.w);
        ((ushort4*)xb)[t] = o;
    }
}

// fallback converter for chunked mode
__global__ void k_convert_x(const float* __restrict__ x, u16* __restrict__ xb, int n4) {
    int i = blockIdx.x * blockDim.x + threadIdx.x;
    if (i >= n4) return;
    float4 v = ((const float4*)x)[i];
    ushort4 o;
    o.x = f2bf(v.x); o.y = f2bf(v.y); o.z = f2bf(v.z); o.w = f2bf(v.w);
    ((ushort4*)xb)[i] = o;
}

// ---------------- GEMM1: X[Tx1024] @ Wbig -> H1 + fused router/value ----------------
// Main loop: m201-style 8-phase ring, verbatim from round-8 (verified).
// Epilogue: bx<9 -> gelu+store h1 (all cols <2304 are gelu). bx==9 -> cols
// 2304-2560 are router+value slices consumed ONLY by router/value: skip h1
// store, stage activated bf16 values in smem ((row&31)<<4 XOR-slot involution;
// read side 2-way = free), then 256 thr do 8-logit softmax rows, 256 thr do
// the value dot + sigmoid. Identical bf16 rounding as the old h1 round-trip.

#define SLOT 8192   // u16 per 16KB slot (128 rows x 64)

__launch_bounds__(512, 2)
__global__ void k_gemm1(const u16* __restrict__ xb, const u16* __restrict__ wbf,
                        const float* __restrict__ biascat, u16* __restrict__ h1,
                        const float* __restrict__ rw2, const float* __restrict__ rb2,
                        const float* __restrict__ vw2, const float* __restrict__ vb2,
                        float* __restrict__ probs_out, float* __restrict__ rtg_out) {
    __shared__ u16 smem[8 * SLOT];   // 128 KB
    __shared__ float rw2s[RH_DIM * E_NUM];
    __shared__ float vws[RH_DIM];
    __shared__ float rb2s[E_NUM];
    const int tid = threadIdx.x;
    const int wid = tid >> 6;
    const int lane = tid & 63;
    const int lin = blockIdx.x;
    const int swz = (lin & 7) * ((int)gridDim.x >> 3) + (lin >> 3);
    const int bx = swz % 10;            // n-tile (NBIG/256 = 10)
    const int by = swz / 10;            // m-tile
    const int m0 = by * 256, n0 = bx * 256;
    const int wr = wid >> 2;
    const int wc = wid & 3;
    const int srow = tid >> 3;
    const int cs = 8 * ((tid & 7) ^ (srow & 7));
    const int l15 = lane & 15;
    const int rsw = (lane & 7) * 8;
    const int lh8 = (lane >> 4) * 8;
    const int c0 = lh8 ^ rsw;
    const int c1 = (32 + lh8) ^ rsw;
    const int aRd = (wr * 16 + l15) * 64;
    const int bRd = ((wc & 1) * 64 + l15) * 64;
    const int bSlotHi = wc >> 1;

    f32x4 acc[8][4];
#pragma unroll
    for (int j = 0; j < 8; ++j)
#pragma unroll
        for (int n = 0; n < 4; ++n) acc[j][n] = (f32x4){0.f, 0.f, 0.f, 0.f};

    auto stageA = [&](int h, int kt, int s) {
        const u16* src = xb + (size_t)(m0 + h * 128 + srow) * H_DIM + kt * 64 + cs;
        u16* dst = smem + s * SLOT + wid * 512;
        gload_lds16(src, dst);
        gload_lds16(src + (size_t)64 * H_DIM, dst + 4096);
    };
    auto stageB = [&](int h, int kt, int s) {
        const u16* src = wbf + (size_t)(n0 + h * 128 + srow) * H_DIM + kt * 64 + cs;
        u16* dst = smem + s * SLOT + wid * 512;
        gload_lds16(src, dst);
        gload_lds16(src + (size_t)64 * H_DIM, dst + 4096);
    };

    bf16x8 bfr[4][2];

#define G1_READA(q, P, A0, A1)                                                    \
    {                                                                             \
        const u16* ab0 = smem + ((P) * 4 + ((q) >> 1)) * SLOT + aRd + (((2*(q)) & 3) * 2048);     \
        const u16* ab1 = smem + ((P) * 4 + ((q) >> 1)) * SLOT + aRd + (((2*(q)+1) & 3) * 2048);   \
        A0[0] = *(const bf16x8*)&ab0[c0]; A0[1] = *(const bf16x8*)&ab0[c1];       \
        A1[0] = *(const bf16x8*)&ab1[c0]; A1[1] = *(const bf16x8*)&ab1[c1];       \
    }

#define G1_MFMA(q, A0, A1)                                                        \
    _Pragma("unroll")                                                             \
    for (int ni = 0; ni < 4; ++ni) {                                              \
        acc[2*(q)][ni]   = __builtin_amdgcn_mfma_f32_16x16x32_bf16(A0[0], bfr[ni][0], acc[2*(q)][ni], 0, 0, 0);   \
        acc[2*(q)][ni]   = __builtin_amdgcn_mfma_f32_16x16x32_bf16(A0[1], bfr[ni][1], acc[2*(q)][ni], 0, 0, 0);   \
        acc[2*(q)+1][ni] = __builtin_amdgcn_mfma_f32_16x16x32_bf16(A1[0], bfr[ni][0], acc[2*(q)+1][ni], 0, 0, 0); \
        acc[2*(q)+1][ni] = __builtin_amdgcn_mfma_f32_16x16x32_bf16(A1[1], bfr[ni][1], acc[2*(q)+1][ni], 0, 0, 0); \
    }

    stageB(0, 0, 2); stageB(1, 0, 3);
    stageA(0, 0, 0); stageA(1, 0, 1);
    stageB(0, 1, 6); stageB(1, 1, 7);
    asm volatile("s_waitcnt vmcnt(6)" ::: "memory");
    __builtin_amdgcn_s_barrier();

#pragma unroll 2
    for (int kt = 0; kt < 16; ++kt) {
        const int p = kt & 1;
        const int ktA = (kt + 1) & 15;
        const int ktB = (kt + 2) & 15;
        const int pA = ktA & 1;
        bf16x8 a0[2], a1[2];
        // ---- P0
        G1_READA(0, p, a0, a1)
#pragma unroll
        for (int ni = 0; ni < 4; ++ni) {
            const u16* bb = smem + (p * 4 + 2 + bSlotHi) * SLOT + bRd + ni * 1024;
            bfr[ni][0] = *(const bf16x8*)&bb[c0];
            bfr[ni][1] = *(const bf16x8*)&bb[c1];
        }
        stageA(0, ktA, pA * 4);
        __builtin_amdgcn_s_barrier();
        asm volatile("s_waitcnt lgkmcnt(0)" ::: "memory");
        __builtin_amdgcn_sched_barrier(0);
        __builtin_amdgcn_s_setprio(1);
        G1_MFMA(0, a0, a1)
        __builtin_amdgcn_s_setprio(0);
        // ---- P1
        G1_READA(1, p, a0, a1)
        stageA(1, ktA, pA * 4 + 1);
        asm volatile("s_waitcnt vmcnt(8)" ::: "memory");
        __builtin_amdgcn_s_barrier();
        asm volatile("s_waitcnt lgkmcnt(0)" ::: "memory");
        __builtin_amdgcn_sched_barrier(0);
        __builtin_amdgcn_s_setprio(1);
        G1_MFMA(1, a0, a1)
        __builtin_amdgcn_s_setprio(0);
        // ---- P2
        G1_READA(2, p, a0, a1)
        stageB(0, ktB, p * 4 + 2);
        __builtin_amdgcn_s_barrier();
        asm volatile("s_waitcnt lgkmcnt(0)" ::: "memory");
        __builtin_amdgcn_sched_barrier(0);
        __builtin_amdgcn_s_setprio(1);
        G1_MFMA(2, a0, a1)
        __builtin_amdgcn_s_setprio(0);
        // ---- P3
        G1_READA(3, p, a0, a1)
        stageB(1, ktB, p * 4 + 3);
        asm volatile("s_waitcnt vmcnt(6)" ::: "memory");
        __builtin_amdgcn_s_barrier();
        asm volatile("s_waitcnt lgkmcnt(0)" ::: "memory");
        __builtin_amdgcn_sched_barrier(0);
        __builtin_amdgcn_s_setprio(1);
        G1_MFMA(3, a0, a1)
        __builtin_amdgcn_s_setprio(0);
    }
#undef G1_READA
#undef G1_MFMA

    const int crow = (lane >> 4) * 4;
    if (bx != 9) {
        // all cols < 2304: expert/shared -> gelu
#pragma unroll
        for (int j = 0; j < 8; ++j) {
#pragma unroll
            for (int ni = 0; ni < 4; ++ni) {
                const int col = n0 + wc * 64 + ni * 16 + l15;
                const float bias = biascat[col];
#pragma unroll
                for (int r = 0; r < 4; ++r) {
                    const int row = m0 + wr * 16 + j * 32 + crow + r;
                    h1[(size_t)row * NBIG + col] = f2bf(gelu_fast(acc[j][ni][r] + bias));
                }
            }
        }
    } else {
        // fused router + value head
        __syncthreads();   // all waves done reading smem (block-uniform branch)
        for (int i = tid; i < RH_DIM * E_NUM; i += 512) rw2s[i] = rw2[i];
        if (tid < RH_DIM) vws[tid] = vw2[tid];
        if (tid < E_NUM) rb2s[tid] = rb2[tid];
        char* sb = (char*)smem;
#pragma unroll
        for (int j = 0; j < 8; ++j) {
#pragma unroll
            for (int ni = 0; ni < 4; ++ni) {
                const int col = wc * 64 + ni * 16 + l15;          // block-local 0..255
                const float bias = biascat[2304 + col];
#pragma unroll
                for (int r = 0; r < 4; ++r) {
                    const int row = wr * 16 + j * 32 + crow + r;  // block-local 0..255
                    float v = acc[j][ni][r] + bias;
                    v = (col < 128) ? gelu_fast(v) : fmaxf(v, 0.f);  // router gelu, value relu
                    *(u16*)(sb + row * 512 + ((col * 2) ^ ((row & 31) << 4))) = f2bf(v);
                }
            }
        }
        __syncthreads();
        if (tid < 256) {
            const int row = tid;
            float lg[E_NUM];
#pragma unroll
            for (int e = 0; e < E_NUM; ++e) lg[e] = rb2s[e];
            const int rx = (row & 31) << 4;
#pragma unroll 4
            for (int s = 0; s < 16; ++s) {
                u16x8 v8 = *(const u16x8*)(sb + row * 512 + ((s << 4) ^ rx));
#pragma unroll
                for (int q = 0; q < 8; ++q) {
                    const float xv = bf2f(v8[q]);
                    const float* wr8 = &rw2s[(s * 8 + q) * E_NUM];
#pragma unroll
                    for (int e = 0; e < E_NUM; ++e) lg[e] = fmaf(xv, wr8[e], lg[e]);
                }
            }
            float mx = lg[0];
#pragma unroll
            for (int e = 1; e < E_NUM; ++e) mx = fmaxf(mx, lg[e]);
            float sm = 0.f;
            float ex[E_NUM];
#pragma unroll
            for (int e = 0; e < E_NUM; ++e) { ex[e] = __expf(lg[e] - mx); sm += ex[e]; }
            const float rs = 1.0f / sm;
#pragma unroll
            for (int e = 0; e < E_NUM; ++e) probs_out[(size_t)(m0 + row) * E_NUM + e] = ex[e] * rs;
        } else {
            const int row = tid - 256;
            const int rx = (row & 31) << 4;
            float pv = 0.f;
#pragma unroll 4
            for (int s = 16; s < 32; ++s) {
                u16x8 v8 = *(const u16x8*)(sb + row * 512 + ((s << 4) ^ rx));
#pragma unroll
                for (int q = 0; q < 8; ++q) pv = fmaf(bf2f(v8[q]), vws[(s - 16) * 8 + q], pv);
            }
            rtg_out[m0 + row] = 1.f / (1.f + __expf(-(pv + vb2[0])));
        }
    }
}

// ---------------- GEMM2: H1[Tx2304] @ W2T^T + prob fold + fused residual MLP + final ----------------
// Main K-loop verbatim from round-8 (verified), LDS re-based into `uni` so the
// dead As/Bs region can be reused by the fused epilogue (moe/rh bf16 tiles).

__launch_bounds__(256, 3)
__global__ void k_gemm2(const u16* __restrict__ h1, const u16* __restrict__ w2t,
                        const float* __restrict__ probs,
                        const float* __restrict__ eb2, const float* __restrict__ sb2,
                        const u16* __restrict__ w1b, const u16* __restrict__ w2b,
                        const float* __restrict__ mb1, const float* __restrict__ mb2,
                        const float* __restrict__ mask, float* __restrict__ out_final) {
    __shared__ u16 uni[12288];          // As[2]@0 (4096 each), Bs[2]@8192 (2048 each); epilogue: Am@0, rh@2560
    __shared__ float plds[64 * E_NUM];
    __shared__ u16 w1s[32 * 128];       // mw1 bf16 [32][128]
    __shared__ u16 w2s[32 * 128];       // mw2^T bf16 [32 cols][128 j]
    const int tid = threadIdx.x;
    const int wid = tid >> 6;
    const int lane = tid & 63;
    const int m0 = blockIdx.x * 64;
    const int csrc = 8 * ((tid & 7) ^ ((tid >> 3) & 7));
    const int rxor = (lane & 7) * 8;
    const int lhi8 = (lane >> 4) * 8;
    const int crow = (lane >> 4) * 4;
    const int ccol = lane & 15;

    for (int i = tid; i < 64 * E_NUM; i += 256) plds[i] = probs[(size_t)m0 * E_NUM + i];
    for (int i = tid; i < 4096; i += 256) { w1s[i] = w1b[i]; w2s[i] = w2b[i]; }

    f32x4 accE[2], accT[2], accS[2];
#pragma unroll
    for (int n = 0; n < 2; ++n) {
        accE[n] = (f32x4){0.f, 0.f, 0.f, 0.f};
        accT[n] = (f32x4){0.f, 0.f, 0.f, 0.f};
        accS[n] = (f32x4){0.f, 0.f, 0.f, 0.f};
    }

    auto stage = [&](int buf, int kt) {
        const int k0 = kt * 64;
#pragma unroll
        for (int j = 0; j < 2; ++j)
            gload_lds16(h1 + (size_t)(m0 + j * 32 + (tid >> 3)) * NBIG + k0 + csrc,
                        &uni[buf * 4096 + j * 2048 + wid * 512]);
        gload_lds16(w2t + (size_t)(tid >> 3) * K2 + k0 + csrc, &uni[8192 + buf * 2048 + wid * 512]);
    };

    stage(0, 0);
    __syncthreads();
    int cur = 0;
    for (int kt = 0; kt < 36; ++kt) {
        if (kt < 35) stage(cur ^ 1, kt + 1);
        const bool isExp = (kt < 32);
#pragma unroll
        for (int kk = 0; kk < 64; kk += 32) {
            bf16x8 av = *(const bf16x8*)&uni[cur * 4096 + (wid * 16 + (lane & 15)) * 64 + ((kk + lhi8) ^ rxor)];
            bf16x8 bv0 = *(const bf16x8*)&uni[8192 + cur * 2048 + ((lane & 15)) * 64 + ((kk + lhi8) ^ rxor)];
            bf16x8 bv1 = *(const bf16x8*)&uni[8192 + cur * 2048 + (16 + (lane & 15)) * 64 + ((kk + lhi8) ^ rxor)];
            if (isExp) {
                accE[0] = __builtin_amdgcn_mfma_f32_16x16x32_bf16(av, bv0, accE[0], 0, 0, 0);
                accE[1] = __builtin_amdgcn_mfma_f32_16x16x32_bf16(av, bv1, accE[1], 0, 0, 0);
            } else {
                accS[0] = __builtin_amdgcn_mfma_f32_16x16x32_bf16(av, bv0, accS[0], 0, 0, 0);
                accS[1] = __builtin_amdgcn_mfma_f32_16x16x32_bf16(av, bv1, accS[1], 0, 0, 0);
            }
        }
        if (isExp && (kt & 3) == 3) {
            const int e = kt >> 2;
#pragma unroll
            for (int r = 0; r < 4; ++r) {
                const float p = plds[(wid * 16 + crow + r) * E_NUM + e];
#pragma unroll
                for (int n = 0; n < 2; ++n) {
                    accT[n][r] += p * accE[n][r];
                    accE[n][r] = 0.f;
                }
            }
        }
        __syncthreads();
        cur ^= 1;
    }

    // ---- fused epilogue: wgt stays in accT; moe -> LDS bf16; scalar MLP; final out
    u16* Am = uni;            // [64][40]
    u16* rhm = uni + 2560;    // [64][136]
    float wgt[2][4];
#pragma unroll
    for (int n = 0; n < 2; ++n) {
        const int aIdx = n * 16 + ccol;
#pragma unroll
        for (int r = 0; r < 4; ++r) {
            const int row = wid * 16 + crow + r;
            float wb = 0.f;
#pragma unroll
            for (int e = 0; e < E_NUM; ++e) wb += plds[row * E_NUM + e] * eb2[e * A_DIM + aIdx];
            const float w = accT[n][r] + wb;
            wgt[n][r] = w;
            Am[row * 40 + aIdx] = f2bf(w + accS[n][r] + sb2[aIdx]);   // moe
        }
    }
    __syncthreads();
    {   // pass 1: rh[row][j] = gelu(moe_row @ mw1 + mb1), thread = (row, 32-col segment)
        const int row = tid >> 2, seg = tid & 3;
        float mrow[32];
#pragma unroll
        for (int a = 0; a < 32; ++a) mrow[a] = bf2f(Am[row * 40 + a]);
#pragma unroll 4
        for (int jj = 0; jj < 32; ++jj) {
            const int j = seg * 32 + jj;
            float s = mb1[j];
#pragma unroll
            for (int a = 0; a < 32; ++a) s = fmaf(mrow[a], bf2f(w1s[a * 128 + j]), s);
            rhm[row * 136 + j] = f2bf(gelu_fast(s));
        }
    }
    __syncthreads();
    // pass 2: final = wgt + rh @ mw2 + mb2, masked
#pragma unroll
    for (int n = 0; n < 2; ++n) {
        const int aIdx = n * 16 + ccol;
        const float b2 = mb2[aIdx];
#pragma unroll
        for (int r = 0; r < 4; ++r) {
            const int row = wid * 16 + crow + r;
            float s = b2;
#pragma unroll
            for (int jc = 0; jc < 16; ++jc) {
                u16x8 rv = *(const u16x8*)&rhm[row * 136 + jc * 8];
                u16x8 wv = *(const u16x8*)&w2s[aIdx * 128 + jc * 8];
#pragma unroll
                for (int q = 0; q < 8; ++q) s = fmaf(bf2f(rv[q]), bf2f(wv[q]), s);
            }
            const int t = m0 + row;
            out_final[(size_t)t * A_DIM + aIdx] = (wgt[n][r] + s) * mask[t];
        }
    }
}

// ---------------- launch ----------------

extern "C" void kernel_launch(void* const* d_in, const int* in_sizes, int n_in,
                              void* d_out, int out_size, void* d_ws, size_t ws_size,
                              hipStream_t stream) {
    const float* state = (const float*)d_in[0];
    const float* base  = (const float*)d_in[1];
    const float* mask  = (const float*)d_in[2];
    const float* sw1 = (const float*)d_in[3];
    const float* sb1 = (const float*)d_in[4];
    const float* sw2 = (const float*)d_in[5];
    const float* sb2 = (const float*)d_in[6];
    const float* ew1 = (const float*)d_in[7];
    const float* eb1 = (const float*)d_in[8];
    const float* ew2 = (const float*)d_in[9];
    const float* eb2 = (const float*)d_in[10];
    const float* rw1 = (const float*)d_in[11];
    const float* rb1 = (const float*)d_in[12];
    const float* rw2 = (const float*)d_in[13];
    const float* rb2 = (const float*)d_in[14];
    const float* mw1 = (const float*)d_in[15];
    const float* mb1 = (const float*)d_in[16];
    const float* mw2 = (const float*)d_in[17];
    const float* mb2 = (const float*)d_in[18];
    const float* vw1 = (const float*)d_in[19];
    const float* vb1 = (const float*)d_in[20];
    const float* vw2 = (const float*)d_in[21];
    const float* vb2 = (const float*)d_in[22];

    float* out_final = (float*)d_out;                 // [32768][32]
    float* out_cand  = out_final + 1048576;           // [32768][8][32]
    float* out_probs = out_final + 9437184;           // [32768][8]
    float* out_rtg   = out_final + 9699328;           // [32768]

    auto al = [](size_t b) { return (b + 255) & ~(size_t)255; };
    auto need = [&](size_t T) {
        return al((size_t)NBIG * H_DIM * 2) + al((size_t)A_DIM * K2 * 2) + al((size_t)NBIG * 4)
             + 2 * al((size_t)4096 * 2)
             + al(T * H_DIM * 2) + al(T * NBIG * 2);
    };
    size_t Tc = 8192;
    if (need(32768) <= ws_size)      Tc = 32768;
    else if (need(16384) <= ws_size) Tc = 16384;
    const int nchunk = (int)(T_TOT / Tc);

    char* ws = (char*)d_ws;
    size_t off = 0;
    auto take = [&](size_t b) { char* p = ws + off; off += (b + 255) & ~(size_t)255; return p; };
    u16*   wbf   = (u16*)take((size_t)NBIG * H_DIM * 2);
    u16*   w2t   = (u16*)take((size_t)A_DIM * K2 * 2);
    float* bias  = (float*)take((size_t)NBIG * 4);
    u16*   w1b   = (u16*)take((size_t)4096 * 2);
    u16*   w2b   = (u16*)take((size_t)4096 * 2);
    u16*   xb    = (u16*)take(Tc * H_DIM * 2);
    u16*   h1    = (u16*)take(Tc * NBIG * 2);
    (void)in_sizes; (void)n_in; (void)out_size;

    const int nconv4 = (Tc == 32768) ? (T_TOT * H_DIM / 4) : 0;
    const int ntot = SW_N4 + nconv4;
    k_setup<<<(ntot + 255) / 256, 256, 0, stream>>>(
        ew1, sw1, rw1, vw1, eb1, sb1, rb1, vb1, ew2, sw2, mw1, mw2,
        base, state, wbf, bias, w2t, w1b, w2b, out_cand, xb, nconv4);

    for (int c = 0; c < nchunk; ++c) {
        const size_t tb = (size_t)c * Tc;
        if (nconv4 == 0)
            k_convert_x<<<(int)(Tc * H_DIM / 4 / 256), 256, 0, stream>>>(state + tb * H_DIM, xb, (int)(Tc * H_DIM / 4));
        k_gemm1<<<10 * (int)(Tc / 256), 512, 0, stream>>>(xb, wbf, bias, h1,
                                                          rw2, rb2, vw2, vb2,
                                                          out_probs + tb * E_NUM, out_rtg + tb);
        k_gemm2<<<(int)(Tc / 64), 256, 0, stream>>>(h1, w2t, out_probs + tb * E_NUM, eb2, sb2,
                                                    w1b, w2b, mb1, mb2, mask + tb, out_final + tb * A_DIM);
    }
}